// Round 12
// baseline (390.310 us; speedup 1.0000x reference)
//
#include <hip/hip_runtime.h>
#include <cstdint>
#include <cstddef>

typedef __bf16 bf16_t;
typedef __bf16 bf16x8 __attribute__((ext_vector_type(8)));
typedef __bf16 bf16x4 __attribute__((ext_vector_type(4)));
typedef __bf16 bf16x2 __attribute__((ext_vector_type(2)));
typedef float f32x4 __attribute__((ext_vector_type(4)));

#define T_LEN 2048
#define DMODEL 4096
#define NHEADS 32
#define KVHEADS 8
#define HD 128
#define QD 4096   // NHEADS*HD
#define KD 1024   // KVHEADS*HD
#define QKVD 6144 // QD + 2*KD
#define WIN 1024
#define VS 72     // padded stride for attn Vt/P tiles (144B = 9*16B)

// ---------------- positions (argmax of segment row, first occurrence) ----------------
__global__ void pos_kernel(const int* __restrict__ seg, int* __restrict__ positions) {
  __shared__ int svals[256], sidx[256];
  int tid = threadIdx.x;
  int bestv = -2147483647 - 1, besti = 0;
  for (int t = tid; t < T_LEN; t += 256) {
    int v = seg[t];
    if (v > bestv) { bestv = v; besti = t; }
  }
  svals[tid] = bestv; sidx[tid] = besti;
  __syncthreads();
  for (int st = 128; st > 0; st >>= 1) {
    if (tid < st) {
      if (svals[tid+st] > svals[tid] || (svals[tid+st] == svals[tid] && sidx[tid+st] < sidx[tid])) {
        svals[tid] = svals[tid+st]; sidx[tid] = sidx[tid+st];
      }
    }
    __syncthreads();
  }
  int amax = sidx[0];
  for (int t = tid; t < T_LEN; t += 256)
    positions[t] = (seg[t] != 0) ? (t - amax) : (1 << 30);
}

// ---------------- rope sin/cos table: sc[t][i][2], i in [0,64) ----------------
__global__ void sincos_kernel(const int* __restrict__ positions, float* __restrict__ sc) {
  int t = blockIdx.x, i = threadIdx.x; // 64 threads
  float inv = expf(-(float)i * (logf(500000.0f) / 64.0f));
  float ang = (float)positions[t] * inv;
  sc[(t*64 + i)*2 + 0] = sinf(ang);
  sc[(t*64 + i)*2 + 1] = cosf(ang);
}

// ---------------- f32 -> bf16 convert (8/thread) ----------------
__global__ void cvt_kernel(const float* __restrict__ in, bf16_t* __restrict__ out, int n) {
  int i = (blockIdx.x * blockDim.x + threadIdx.x) * 8;
  if (i >= n) return;
  float4 a = *(const float4*)(in + i);
  float4 b = *(const float4*)(in + i + 4);
  bf16x8 o;
  o[0]=(bf16_t)a.x; o[1]=(bf16_t)a.y; o[2]=(bf16_t)a.z; o[3]=(bf16_t)a.w;
  o[4]=(bf16_t)b.x; o[5]=(bf16_t)b.y; o[6]=(bf16_t)b.z; o[7]=(bf16_t)b.w;
  *(bf16x8*)(out + i) = o;
}

// ---------------- transpose + convert: W[K][N] f32 -> Wt[N][K] bf16 ----------------
__global__ void transcvt_kernel(const float* __restrict__ W, bf16_t* __restrict__ Wt, int K, int N) {
  __shared__ float tile[32][33];
  int tx = threadIdx.x, ty = threadIdx.y; // 32 x 8
  int bx = blockIdx.x, by = blockIdx.y;
  #pragma unroll
  for (int i = 0; i < 4; i++) {
    int k = by*32 + ty + i*8;
    tile[ty + i*8][tx] = W[(size_t)k * N + bx*32 + tx];
  }
  __syncthreads();
  int t = ty*32 + tx;   // 0..255
  int n = t >> 3;       // 0..31
  int kq = t & 7;       // quad-of-4 k
  bf16x4 v;
  #pragma unroll
  for (int e = 0; e < 4; e++) v[e] = (bf16_t)tile[kq*4 + e][n];
  *(bf16x4*)(Wt + (size_t)(bx*32 + n) * K + by*32 + kq*4) = v;
}

// ---------------- 8-phase bf16 GEMM (T1+T2+T3+T4+T5), BM = AM*128, BN = 256 ----------------
__device__ __forceinline__ void gld_lds16(const void* g, void* l) {
  __builtin_amdgcn_global_load_lds((__attribute__((address_space(1))) void*)g,
                                   (__attribute__((address_space(3))) void*)l, 16, 0, 0);
}

#define MFMA_QUAD(FM0, FN0)                                                     \
  { _Pragma("unroll") for (int fm_ = 0; fm_ < QFM; fm_++)                        \
    _Pragma("unroll") for (int fn_ = 0; fn_ < 2; fn_++)                          \
    _Pragma("unroll") for (int kk_ = 0; kk_ < 2; kk_++)                          \
      acc[(FM0)+fm_][(FN0)+fn_] = __builtin_amdgcn_mfma_f32_16x16x32_bf16(       \
          a[(FM0)+fm_][kk_], bb[(FN0)+fn_][kk_], acc[(FM0)+fm_][(FN0)+fn_], 0,0,0); }

template<bool WRITE_BF16, int AM>  // AM=2: 256x256; AM=1: 128x256
__global__ __launch_bounds__(512, 2) void gemm256_kernel(
    const bf16_t* __restrict__ A, const bf16_t* __restrict__ Bt,
    bf16_t* __restrict__ Cb, float* __restrict__ Cf,
    int M, int N, int K, int NBM) {
  constexpr int BM  = AM * 128;
  constexpr int NH  = AM + 2;
  constexpr int FM2 = AM * 4;
  constexpr int QFM = AM * 2;
  __shared__ bf16_t As[2 * BM * 64];
  __shared__ bf16_t Bs[2 * 256 * 64];
  int tid = threadIdx.x;
  int w = tid >> 6, l = tid & 63, lr = l & 15, lg = l >> 4;
  int wr = w >> 2, wc = w & 3;
  int nwg = gridDim.x;
  int wg  = blockIdx.x;
  int cpx = nwg >> 3;
  int swz = (wg & 7) * cpx + (wg >> 3);
  int bm = swz % NBM, bn = swz / NBM;   // bm fast, bn slow (L2: few B-panels/XCD)
  const int NT = K >> 6;

  auto stage = [&](int tt, int h) {
    int b2 = tt & 1;
    const bf16_t* G; size_t grow0; bf16_t* ldsb;
    if (h < AM) { G = A;  grow0 = (size_t)bm*BM + h*128;        ldsb = As + b2*(BM*64) + h*8192; }
    else        { G = Bt; grow0 = (size_t)bn*256 + (h-AM)*128;  ldsb = Bs + b2*16384 + (h-AM)*8192; }
    int kcol = tt * 64;
    #pragma unroll
    for (int r2 = 0; r2 < 2; r2++) {
      int L = r2*8192 + tid*16;
      int row = L >> 7;
      int chunk = (L >> 4) & 7;
      int scn = chunk ^ (row & 7);
      gld_lds16(G + (grow0 + (size_t)row) * K + kcol + scn*8,
                ldsb + r2*4096 + w*512);
    }
  };
  auto afrag = [&](int b2, int row, int kk) -> bf16x8 {
    int chunk = (kk*4 + lg) ^ (row & 7);
    return *(const bf16x8*)((const char*)(As + b2*(BM*64)) + row*128 + chunk*16);
  };
  auto bfrag = [&](int b2, int row, int kk) -> bf16x8 {
    int chunk = (kk*4 + lg) ^ (row & 7);
    return *(const bf16x8*)((const char*)(Bs + b2*16384) + row*128 + chunk*16);
  };

  f32x4 acc[FM2][4] = {};
  bf16x8 a[FM2][2], bb[4][2];

  #pragma unroll
  for (int h = 0; h < NH; h++) stage(0, h);
  #pragma unroll
  for (int h = 0; h < NH - 1; h++) stage(1, h);
  if constexpr (AM == 2) asm volatile("s_waitcnt vmcnt(6)" ::: "memory");
  else                   asm volatile("s_waitcnt vmcnt(4)" ::: "memory");
  __builtin_amdgcn_s_barrier();

  for (int t = 0; t < NT; t++) {
    int b = t & 1;
    #pragma unroll
    for (int fm = 0; fm < FM2; fm++)
      #pragma unroll
      for (int kk = 0; kk < 2; kk++)
        a[fm][kk] = afrag(b, wr*(BM/2) + fm*16 + lr, kk);
    #pragma unroll
    for (int fn = 0; fn < 2; fn++)
      #pragma unroll
      for (int kk = 0; kk < 2; kk++)
        bb[fn][kk] = bfrag(b, wc*64 + fn*16 + lr, kk);
    if (t + 1 < NT) stage(t + 1, NH - 1);
    __builtin_amdgcn_s_barrier();
    asm volatile("s_waitcnt lgkmcnt(0)" ::: "memory");
    __builtin_amdgcn_s_setprio(1);
    MFMA_QUAD(0, 0);
    __builtin_amdgcn_s_setprio(0);
    __builtin_amdgcn_s_barrier();
    #pragma unroll
    for (int fn = 2; fn < 4; fn++)
      #pragma unroll
      for (int kk = 0; kk < 2; kk++)
        bb[fn][kk] = bfrag(b, wc*64 + fn*16 + lr, kk);
    if (t + 2 < NT) stage(t + 2, 0);
    __builtin_amdgcn_s_barrier();
    asm volatile("s_waitcnt lgkmcnt(0)" ::: "memory");
    __builtin_amdgcn_s_setprio(1);
    MFMA_QUAD(0, 2);
    __builtin_amdgcn_s_setprio(0);
    __builtin_amdgcn_s_barrier();
    if (t + 2 < NT) stage(t + 2, 1);
    __builtin_amdgcn_s_barrier();
    __builtin_amdgcn_s_setprio(1);
    MFMA_QUAD(QFM, 2);
    __builtin_amdgcn_s_setprio(0);
    __builtin_amdgcn_s_barrier();
    if constexpr (AM == 2) { if (t + 2 < NT) stage(t + 2, 2); }
    __builtin_amdgcn_s_barrier();
    __builtin_amdgcn_s_setprio(1);
    MFMA_QUAD(QFM, 0);
    __builtin_amdgcn_s_setprio(0);
    if (t < NT - 2) {
      if constexpr (AM == 2) asm volatile("s_waitcnt vmcnt(6)" ::: "memory");
      else                   asm volatile("s_waitcnt vmcnt(4)" ::: "memory");
    } else {
      asm volatile("s_waitcnt vmcnt(0)" ::: "memory");
    }
    __builtin_amdgcn_s_barrier();
  }

  #pragma unroll
  for (int fm = 0; fm < FM2; fm++) {
    #pragma unroll
    for (int fn = 0; fn < 4; fn++) {
      #pragma unroll
      for (int r2 = 0; r2 < 4; r2++) {
        int row = bm*BM + wr*(BM/2) + fm*16 + lg*4 + r2;
        int col = bn*256 + wc*64 + fn*16 + lr;
        if (WRITE_BF16) Cb[(size_t)row * N + col] = (bf16_t)acc[fm][fn][r2];
        else            Cf[(size_t)row * N + col] = acc[fm][fn][r2];
      }
    }
  }
}

// ---------------- fused RMSNorm (q over 4096, k over 1024) + RoPE + q-scale ----------------
__global__ __launch_bounds__(256) void normrope_kernel(bf16_t* __restrict__ qkv,
    const float* __restrict__ qw, const float* __restrict__ kw,
    const float* __restrict__ sc) {
  int t = blockIdx.x;
  int tid = threadIdx.x;
  bf16_t* qrow = qkv + (size_t)t * QKVD;
  bf16_t* krow = qrow + QD;
  __shared__ float red[8];
  float s = 0.f;
  {
    const bf16x8* p = (const bf16x8*)(qrow + tid*16);
    bf16x8 v0 = p[0], v1 = p[1];
    #pragma unroll
    for (int j = 0; j < 8; j++) { float a = (float)v0[j], b = (float)v1[j]; s += a*a + b*b; }
  }
  #pragma unroll
  for (int o = 32; o; o >>= 1) s += __shfl_xor(s, o);
  if ((tid & 63) == 0) red[tid >> 6] = s;
  float sk = 0.f;
  {
    bf16x4 v = *(const bf16x4*)(krow + tid*4);
    #pragma unroll
    for (int j = 0; j < 4; j++) { float a = (float)v[j]; sk += a*a; }
  }
  #pragma unroll
  for (int o = 32; o; o >>= 1) sk += __shfl_xor(sk, o);
  if ((tid & 63) == 0) red[4 + (tid >> 6)] = sk;
  __syncthreads();
  float rq = rsqrtf((red[0]+red[1]+red[2]+red[3]) / (float)QD + 1e-6f);
  float rk = rsqrtf((red[4]+red[5]+red[6]+red[7]) / (float)KD + 1e-6f);
  const float ascale = 0.08838834764831845f; // 1/sqrt(128), folded into Q
  for (int p = tid; p < 2048; p += 256) {
    int hh = p >> 6, i = p & 63;
    int i1 = hh*HD + i, i2 = i1 + 64;
    float x1 = (float)qrow[i1] * rq * qw[i1];
    float x2 = (float)qrow[i2] * rq * qw[i2];
    float sn = sc[(t*64 + i)*2 + 0], cs = sc[(t*64 + i)*2 + 1];
    qrow[i1] = (bf16_t)((x1*cs - x2*sn) * ascale);
    qrow[i2] = (bf16_t)((x2*cs + x1*sn) * ascale);
  }
  for (int p = tid; p < 512; p += 256) {
    int hh = p >> 6, i = p & 63;
    int i1 = hh*HD + i, i2 = i1 + 64;
    float x1 = (float)krow[i1] * rk * kw[i1];
    float x2 = (float)krow[i2] * rk * kw[i2];
    float sn = sc[(t*64 + i)*2 + 0], cs = sc[(t*64 + i)*2 + 1];
    krow[i1] = (bf16_t)(x1*cs - x2*sn);
    krow[i2] = (bf16_t)(x2*cs + x1*sn);
  }
}

// ---------------- flash attention, sliding window, GQA ----------------
// QB=128: 8 waves x 16 q rows, KV tile = 64 keys. Same inner structure as the
// R9-proven kernel; block-tile count halves (13056 -> 6912), so staging,
// barriers and K/V L2 traffic per useful FLOP halve. vmcnt queue mirrors R9:
// [K(2) masks(8) V(2)] -> vmcnt(2) drains K+masks, keeps V(t+1) in flight.
__global__ __launch_bounds__(512, 3) void attn_kernel(const bf16_t* __restrict__ qkv,
    const int* __restrict__ positions, const int* __restrict__ seg,
    bf16_t* __restrict__ O) {
  __shared__ bf16_t Ks[64 * HD];      // 16 KB, 16B-chunk XOR swizzle (linear dest, pre-swizzled src)
  __shared__ bf16_t Vt[HD * VS];      // 18 KB, V transposed [128 d][64 keys + pad]
  __shared__ bf16_t P[8][16 * VS];    // 18 KB, per-wave P tile
  int tid = threadIdx.x;
  int w = tid >> 6, l = tid & 63, lr = l & 15, lg = l >> 4;
  int qb = blockIdx.x * 128;
  int h = blockIdx.y;
  int kvh = h >> 2;
  int q0 = qb + w * 16;
  const bf16_t* Kg = qkv + QD + (size_t)kvh * HD;
  const bf16_t* Vg = qkv + QD + KD + (size_t)kvh * HD;

  bf16x8 qf[4];
  {
    const bf16_t* Qrow = qkv + (size_t)(q0 + lr) * QKVD + h * HD;
    #pragma unroll
    for (int c = 0; c < 4; c++) qf[c] = *(const bf16x8*)(Qrow + c*32 + lg*8);
  }
  int pos_i[4], seg_i[4];
  #pragma unroll
  for (int r = 0; r < 4; r++) { int i = q0 + lg*4 + r; pos_i[r] = positions[i]; seg_i[r] = seg[i]; }
  f32x4 o[8] = {};
  float m[4], lsum[4];
  #pragma unroll
  for (int r = 0; r < 4; r++) { m[r] = -__builtin_inff(); lsum[r] = 0.f; }

  // V item: key-pair + d-group (512 items, 1 per thread)
  int vkp = tid & 31, vdg = tid >> 5;
  bf16x8 vrA, vrB;

  // K staging: 1024 16B-chunks over 512 threads x 2
  auto issueK = [&](int j0) {
    #pragma unroll
    for (int i = 0; i < 2; i++) {
      int c = tid + i*512;
      int row = c >> 4;
      int scn = (c & 15) ^ (row & 7);
      gld_lds16(Kg + (size_t)(j0 + row) * QKVD + scn*8,
                (char*)Ks + (size_t)(i*512 + (tid & 448))*16);
    }
  };
  auto loadV = [&](int j0) {
    const bf16_t* vp = Vg + (size_t)(j0 + 2*vkp) * QKVD + vdg*8;
    vrA = *(const bf16x8*)vp;
    vrB = *(const bf16x8*)(vp + QKVD);
  };

  int jstart = qb - (WIN - 1); if (jstart < 0) jstart = 0; jstart &= ~63;
  const int jlast = qb + 64;   // covers rows up to qb+127
  loadV(jstart);
  issueK(jstart);

  for (int j0 = jstart; j0 <= jlast; j0 += 64) {
    // ---- Phase A: commit V(t); mask loads; prefetch V(t+1); drain K ----
    #pragma unroll
    for (int e = 0; e < 8; e++) {
      bf16x2 pr; pr[0] = vrA[e]; pr[1] = vrB[e];
      *(bf16x2*)(Vt + (vdg*8 + e)*VS + 2*vkp) = pr;
    }
    int pj[4], sj[4];
    #pragma unroll
    for (int kt = 0; kt < 4; kt++) { int j = j0 + kt*16 + lr; pj[kt] = positions[j]; sj[kt] = seg[j]; }
    asm volatile("" ::: "memory");
    if (j0 + 64 <= jlast) loadV(j0 + 64);
    asm volatile("" ::: "memory");
    asm volatile("s_waitcnt vmcnt(2) lgkmcnt(0)" ::: "memory");
    __builtin_amdgcn_s_barrier();

    // ---- Phase B: QK^T + softmax + P ----
    bool active = (j0 <= q0 + 15) && (j0 + 63 >= q0 - (WIN - 1));
    if (active) {
      f32x4 s[4] = {};
      #pragma unroll
      for (int kt = 0; kt < 4; kt++) {
        int row = kt*16 + lr;
        const char* kb = (const char*)Ks + row*256;
        #pragma unroll
        for (int c = 0; c < 4; c++) {
          bf16x8 kf = *(const bf16x8*)(kb + (((c*4 + lg) ^ (row & 7)) * 16));
          s[kt] = __builtin_amdgcn_mfma_f32_16x16x32_bf16(qf[c], kf, s[kt], 0, 0, 0);
        }
      }
      #pragma unroll
      for (int kt = 0; kt < 4; kt++) {
        #pragma unroll
        for (int r = 0; r < 4; r++) {
          bool valid = (pj[kt] <= pos_i[r]) && (pos_i[r] - pj[kt] < WIN) && (seg_i[r] == sj[kt]) && (sj[kt] != 0);
          s[kt][r] = valid ? s[kt][r] : -__builtin_inff();
        }
      }
      #pragma unroll
      for (int r = 0; r < 4; r++) {
        float rm = fmaxf(fmaxf(s[0][r], s[1][r]), fmaxf(s[2][r], s[3][r]));
        #pragma unroll
        for (int o2 = 1; o2 < 16; o2 <<= 1) rm = fmaxf(rm, __shfl_xor(rm, o2));
        if (rm > m[r] + 8.f) {
          float rescale = __expf(m[r] - rm);
          lsum[r] *= rescale;
          #pragma unroll
          for (int n = 0; n < 8; n++) o[n][r] *= rescale;
          m[r] = rm;
        }
        float mub = fmaxf(m[r], -1e37f);
        float p0 = __expf(s[0][r] - mub);
        float p1 = __expf(s[1][r] - mub);
        float p2 = __expf(s[2][r] - mub);
        float p3 = __expf(s[3][r] - mub);
        float rs = (p0 + p1) + (p2 + p3);
        #pragma unroll
        for (int o2 = 1; o2 < 16; o2 <<= 1) rs += __shfl_xor(rs, o2);
        lsum[r] += rs;
        int prow = (lg*4 + r) * VS;
        P[w][prow + lr]      = (bf16_t)p0;
        P[w][prow + 16 + lr] = (bf16_t)p1;
        P[w][prow + 32 + lr] = (bf16_t)p2;
        P[w][prow + 48 + lr] = (bf16_t)p3;
      }
    }
    __builtin_amdgcn_s_barrier();
    asm volatile("" ::: "memory");

    // ---- Phase C: issue K(t+1); PV ----
    if (j0 + 64 <= jlast) issueK(j0 + 64);
    if (active) {
      #pragma unroll
      for (int ks = 0; ks < 2; ks++) {
        bf16x8 pa = *(const bf16x8*)(&P[w][lr*VS + ks*32 + lg*8]);
        #pragma unroll
        for (int n = 0; n < 8; n++) {
          bf16x8 vb = *(const bf16x8*)(&Vt[(n*16 + lr)*VS + ks*32 + lg*8]);
          o[n] = __builtin_amdgcn_mfma_f32_16x16x32_bf16(pa, vb, o[n], 0, 0, 0);
        }
      }
    }
    __builtin_amdgcn_s_barrier();
  }
  #pragma unroll
  for (int r = 0; r < 4; r++) {
    float inv = lsum[r] > 0.f ? 1.f / lsum[r] : 0.f;
    int row = q0 + lg*4 + r;
    #pragma unroll
    for (int n = 0; n < 8; n++)
      O[(size_t)row * QD + h*HD + n*16 + lr] = (bf16_t)(o[n][r] * inv);
  }
}

// ---------------- launch ----------------
extern "C" void kernel_launch(void* const* d_in, const int* in_sizes, int n_in,
                              void* d_out, int out_size, void* d_ws, size_t ws_size,
                              hipStream_t stream) {
  (void)in_sizes; (void)n_in; (void)out_size; (void)ws_size;
  const float* x  = (const float*)d_in[0];
  const float* Wq = (const float*)d_in[1];
  const float* Wk = (const float*)d_in[2];
  const float* Wv = (const float*)d_in[3];
  const float* Wo = (const float*)d_in[4];
  const float* qw = (const float*)d_in[5];
  const float* kw = (const float*)d_in[6];
  const int*  seg = (const int*)d_in[7];
  float* out = (float*)d_out;

  char* base = (char*)d_ws;
  size_t off = 0;
  auto alloc = [&](size_t b) { void* r = base + off; off = (off + b + 255) & ~(size_t)255; return r; };
  bf16_t* xb    = (bf16_t*)alloc((size_t)T_LEN * DMODEL * 2);
  bf16_t* Wallt = (bf16_t*)alloc((size_t)QKVD * DMODEL * 2);
  bf16_t* Wot   = (bf16_t*)alloc((size_t)DMODEL * QD * 2);
  bf16_t* qkv   = (bf16_t*)alloc((size_t)T_LEN * QKVD * 2);
  int*    posi  = (int*)alloc((size_t)T_LEN * 4);
  float*  sc    = (float*)alloc((size_t)T_LEN * 64 * 2 * 4);
  bf16_t* ao    = xb;  // attention output aliases xb (xb dead after GEMM1)

  pos_kernel<<<1, 256, 0, stream>>>(seg, posi);
  sincos_kernel<<<T_LEN, 64, 0, stream>>>(posi, sc);
  cvt_kernel<<<(T_LEN * DMODEL / 8 + 255) / 256, 256, 0, stream>>>(x, xb, T_LEN * DMODEL);
  transcvt_kernel<<<dim3(QD/32, DMODEL/32), dim3(32, 8), 0, stream>>>(Wq, Wallt, DMODEL, QD);
  transcvt_kernel<<<dim3(KD/32, DMODEL/32), dim3(32, 8), 0, stream>>>(Wk, Wallt + (size_t)QD * DMODEL, DMODEL, KD);
  transcvt_kernel<<<dim3(KD/32, DMODEL/32), dim3(32, 8), 0, stream>>>(Wv, Wallt + (size_t)(QD + KD) * DMODEL, DMODEL, KD);
  transcvt_kernel<<<dim3(DMODEL/32, QD/32), dim3(32, 8), 0, stream>>>(Wo, Wot, QD, DMODEL);
  gemm256_kernel<true, 2><<<dim3((T_LEN/256)*(QKVD/256)), 512, 0, stream>>>(
      xb, Wallt, qkv, nullptr, T_LEN, QKVD, DMODEL, T_LEN/256);
  normrope_kernel<<<T_LEN, 256, 0, stream>>>(qkv, qw, kw, sc);
  attn_kernel<<<dim3(T_LEN/128, NHEADS), 512, 0, stream>>>(qkv, posi, seg, ao);
  gemm256_kernel<false, 1><<<dim3((T_LEN/128)*(DMODEL/256)), 512, 0, stream>>>(
      ao, Wot, nullptr, out, T_LEN, DMODEL, QD, T_LEN/128);
}

// Round 13
// 375.577 us; speedup vs baseline: 1.0392x; 1.0392x over previous
//
#include <hip/hip_runtime.h>
#include <cstdint>
#include <cstddef>

typedef __bf16 bf16_t;
typedef __bf16 bf16x8 __attribute__((ext_vector_type(8)));
typedef __bf16 bf16x4 __attribute__((ext_vector_type(4)));
typedef __bf16 bf16x2 __attribute__((ext_vector_type(2)));
typedef float f32x4 __attribute__((ext_vector_type(4)));

#define T_LEN 2048
#define DMODEL 4096
#define NHEADS 32
#define KVHEADS 8
#define HD 128
#define QD 4096   // NHEADS*HD
#define KD 1024   // KVHEADS*HD
#define QKVD 6144 // QD + 2*KD
#define WIN 1024
#define VS 72     // padded stride for attn Vt/P tiles (144B = 9*16B)

// ---------------- positions (argmax of segment row, first occurrence) ----------------
__global__ void pos_kernel(const int* __restrict__ seg, int* __restrict__ positions) {
  __shared__ int svals[256], sidx[256];
  int tid = threadIdx.x;
  int bestv = -2147483647 - 1, besti = 0;
  for (int t = tid; t < T_LEN; t += 256) {
    int v = seg[t];
    if (v > bestv) { bestv = v; besti = t; }
  }
  svals[tid] = bestv; sidx[tid] = besti;
  __syncthreads();
  for (int st = 128; st > 0; st >>= 1) {
    if (tid < st) {
      if (svals[tid+st] > svals[tid] || (svals[tid+st] == svals[tid] && sidx[tid+st] < sidx[tid])) {
        svals[tid] = svals[tid+st]; sidx[tid] = sidx[tid+st];
      }
    }
    __syncthreads();
  }
  int amax = sidx[0];
  for (int t = tid; t < T_LEN; t += 256)
    positions[t] = (seg[t] != 0) ? (t - amax) : (1 << 30);
}

// ---------------- rope sin/cos table: sc[t][i][2], i in [0,64) ----------------
__global__ void sincos_kernel(const int* __restrict__ positions, float* __restrict__ sc) {
  int t = blockIdx.x, i = threadIdx.x; // 64 threads
  float inv = expf(-(float)i * (logf(500000.0f) / 64.0f));
  float ang = (float)positions[t] * inv;
  sc[(t*64 + i)*2 + 0] = sinf(ang);
  sc[(t*64 + i)*2 + 1] = cosf(ang);
}

// ---------------- f32 -> bf16 convert (8/thread) ----------------
__global__ void cvt_kernel(const float* __restrict__ in, bf16_t* __restrict__ out, int n) {
  int i = (blockIdx.x * blockDim.x + threadIdx.x) * 8;
  if (i >= n) return;
  float4 a = *(const float4*)(in + i);
  float4 b = *(const float4*)(in + i + 4);
  bf16x8 o;
  o[0]=(bf16_t)a.x; o[1]=(bf16_t)a.y; o[2]=(bf16_t)a.z; o[3]=(bf16_t)a.w;
  o[4]=(bf16_t)b.x; o[5]=(bf16_t)b.y; o[6]=(bf16_t)b.z; o[7]=(bf16_t)b.w;
  *(bf16x8*)(out + i) = o;
}

// ---------------- transpose + convert: W[K][N] f32 -> Wt[N][K] bf16 ----------------
__global__ void transcvt_kernel(const float* __restrict__ W, bf16_t* __restrict__ Wt, int K, int N) {
  __shared__ float tile[32][33];
  int tx = threadIdx.x, ty = threadIdx.y; // 32 x 8
  int bx = blockIdx.x, by = blockIdx.y;
  #pragma unroll
  for (int i = 0; i < 4; i++) {
    int k = by*32 + ty + i*8;
    tile[ty + i*8][tx] = W[(size_t)k * N + bx*32 + tx];
  }
  __syncthreads();
  int t = ty*32 + tx;   // 0..255
  int n = t >> 3;       // 0..31
  int kq = t & 7;       // quad-of-4 k
  bf16x4 v;
  #pragma unroll
  for (int e = 0; e < 4; e++) v[e] = (bf16_t)tile[kq*4 + e][n];
  *(bf16x4*)(Wt + (size_t)(bx*32 + n) * K + by*32 + kq*4) = v;
}

// ---------------- 8-phase bf16 GEMM (T1+T2+T3+T4+T5), BM = AM*128, BN = 256 ----------------
__device__ __forceinline__ void gld_lds16(const void* g, void* l) {
  __builtin_amdgcn_global_load_lds((__attribute__((address_space(1))) void*)g,
                                   (__attribute__((address_space(3))) void*)l, 16, 0, 0);
}

#define MFMA_QUAD(FM0, FN0)                                                     \
  { _Pragma("unroll") for (int fm_ = 0; fm_ < QFM; fm_++)                        \
    _Pragma("unroll") for (int fn_ = 0; fn_ < 2; fn_++)                          \
    _Pragma("unroll") for (int kk_ = 0; kk_ < 2; kk_++)                          \
      acc[(FM0)+fm_][(FN0)+fn_] = __builtin_amdgcn_mfma_f32_16x16x32_bf16(       \
          a[(FM0)+fm_][kk_], bb[(FN0)+fn_][kk_], acc[(FM0)+fm_][(FN0)+fn_], 0,0,0); }

template<bool WRITE_BF16, int AM>  // AM=2: 256x256; AM=1: 128x256
__global__ __launch_bounds__(512, 2) void gemm256_kernel(
    const bf16_t* __restrict__ A, const bf16_t* __restrict__ Bt,
    bf16_t* __restrict__ Cb, float* __restrict__ Cf,
    int M, int N, int K, int NBM) {
  constexpr int BM  = AM * 128;
  constexpr int NH  = AM + 2;
  constexpr int FM2 = AM * 4;
  constexpr int QFM = AM * 2;
  __shared__ bf16_t As[2 * BM * 64];
  __shared__ bf16_t Bs[2 * 256 * 64];
  int tid = threadIdx.x;
  int w = tid >> 6, l = tid & 63, lr = l & 15, lg = l >> 4;
  int wr = w >> 2, wc = w & 3;
  int nwg = gridDim.x;
  int wg  = blockIdx.x;
  int cpx = nwg >> 3;
  int swz = (wg & 7) * cpx + (wg >> 3);
  int bm = swz % NBM, bn = swz / NBM;   // bm fast, bn slow (L2: few B-panels/XCD)
  const int NT = K >> 6;

  auto stage = [&](int tt, int h) {
    int b2 = tt & 1;
    const bf16_t* G; size_t grow0; bf16_t* ldsb;
    if (h < AM) { G = A;  grow0 = (size_t)bm*BM + h*128;        ldsb = As + b2*(BM*64) + h*8192; }
    else        { G = Bt; grow0 = (size_t)bn*256 + (h-AM)*128;  ldsb = Bs + b2*16384 + (h-AM)*8192; }
    int kcol = tt * 64;
    #pragma unroll
    for (int r2 = 0; r2 < 2; r2++) {
      int L = r2*8192 + tid*16;
      int row = L >> 7;
      int chunk = (L >> 4) & 7;
      int scn = chunk ^ (row & 7);
      gld_lds16(G + (grow0 + (size_t)row) * K + kcol + scn*8,
                ldsb + r2*4096 + w*512);
    }
  };
  auto afrag = [&](int b2, int row, int kk) -> bf16x8 {
    int chunk = (kk*4 + lg) ^ (row & 7);
    return *(const bf16x8*)((const char*)(As + b2*(BM*64)) + row*128 + chunk*16);
  };
  auto bfrag = [&](int b2, int row, int kk) -> bf16x8 {
    int chunk = (kk*4 + lg) ^ (row & 7);
    return *(const bf16x8*)((const char*)(Bs + b2*16384) + row*128 + chunk*16);
  };

  f32x4 acc[FM2][4] = {};
  bf16x8 a[FM2][2], bb[4][2];

  #pragma unroll
  for (int h = 0; h < NH; h++) stage(0, h);
  #pragma unroll
  for (int h = 0; h < NH - 1; h++) stage(1, h);
  if constexpr (AM == 2) asm volatile("s_waitcnt vmcnt(6)" ::: "memory");
  else                   asm volatile("s_waitcnt vmcnt(4)" ::: "memory");
  __builtin_amdgcn_s_barrier();

  for (int t = 0; t < NT; t++) {
    int b = t & 1;
    #pragma unroll
    for (int fm = 0; fm < FM2; fm++)
      #pragma unroll
      for (int kk = 0; kk < 2; kk++)
        a[fm][kk] = afrag(b, wr*(BM/2) + fm*16 + lr, kk);
    #pragma unroll
    for (int fn = 0; fn < 2; fn++)
      #pragma unroll
      for (int kk = 0; kk < 2; kk++)
        bb[fn][kk] = bfrag(b, wc*64 + fn*16 + lr, kk);
    if (t + 1 < NT) stage(t + 1, NH - 1);
    __builtin_amdgcn_s_barrier();
    asm volatile("s_waitcnt lgkmcnt(0)" ::: "memory");
    __builtin_amdgcn_s_setprio(1);
    MFMA_QUAD(0, 0);
    __builtin_amdgcn_s_setprio(0);
    __builtin_amdgcn_s_barrier();
    #pragma unroll
    for (int fn = 2; fn < 4; fn++)
      #pragma unroll
      for (int kk = 0; kk < 2; kk++)
        bb[fn][kk] = bfrag(b, wc*64 + fn*16 + lr, kk);
    if (t + 2 < NT) stage(t + 2, 0);
    __builtin_amdgcn_s_barrier();
    asm volatile("s_waitcnt lgkmcnt(0)" ::: "memory");
    __builtin_amdgcn_s_setprio(1);
    MFMA_QUAD(0, 2);
    __builtin_amdgcn_s_setprio(0);
    __builtin_amdgcn_s_barrier();
    if (t + 2 < NT) stage(t + 2, 1);
    __builtin_amdgcn_s_barrier();
    __builtin_amdgcn_s_setprio(1);
    MFMA_QUAD(QFM, 2);
    __builtin_amdgcn_s_setprio(0);
    __builtin_amdgcn_s_barrier();
    if constexpr (AM == 2) { if (t + 2 < NT) stage(t + 2, 2); }
    __builtin_amdgcn_s_barrier();
    __builtin_amdgcn_s_setprio(1);
    MFMA_QUAD(QFM, 0);
    __builtin_amdgcn_s_setprio(0);
    if (t < NT - 2) {
      if constexpr (AM == 2) asm volatile("s_waitcnt vmcnt(6)" ::: "memory");
      else                   asm volatile("s_waitcnt vmcnt(4)" ::: "memory");
    } else {
      asm volatile("s_waitcnt vmcnt(0)" ::: "memory");
    }
    __builtin_amdgcn_s_barrier();
  }

  #pragma unroll
  for (int fm = 0; fm < FM2; fm++) {
    #pragma unroll
    for (int fn = 0; fn < 4; fn++) {
      #pragma unroll
      for (int r2 = 0; r2 < 4; r2++) {
        int row = bm*BM + wr*(BM/2) + fm*16 + lg*4 + r2;
        int col = bn*256 + wc*64 + fn*16 + lr;
        if (WRITE_BF16) Cb[(size_t)row * N + col] = (bf16_t)acc[fm][fn][r2];
        else            Cf[(size_t)row * N + col] = acc[fm][fn][r2];
      }
    }
  }
}

// ---------------- fused RMSNorm (q over 4096, k over 1024) + RoPE + q-scale ----------------
__global__ __launch_bounds__(256) void normrope_kernel(bf16_t* __restrict__ qkv,
    const float* __restrict__ qw, const float* __restrict__ kw,
    const float* __restrict__ sc) {
  int t = blockIdx.x;
  int tid = threadIdx.x;
  bf16_t* qrow = qkv + (size_t)t * QKVD;
  bf16_t* krow = qrow + QD;
  __shared__ float red[8];
  float s = 0.f;
  {
    const bf16x8* p = (const bf16x8*)(qrow + tid*16);
    bf16x8 v0 = p[0], v1 = p[1];
    #pragma unroll
    for (int j = 0; j < 8; j++) { float a = (float)v0[j], b = (float)v1[j]; s += a*a + b*b; }
  }
  #pragma unroll
  for (int o = 32; o; o >>= 1) s += __shfl_xor(s, o);
  if ((tid & 63) == 0) red[tid >> 6] = s;
  float sk = 0.f;
  {
    bf16x4 v = *(const bf16x4*)(krow + tid*4);
    #pragma unroll
    for (int j = 0; j < 4; j++) { float a = (float)v[j]; sk += a*a; }
  }
  #pragma unroll
  for (int o = 32; o; o >>= 1) sk += __shfl_xor(sk, o);
  if ((tid & 63) == 0) red[4 + (tid >> 6)] = sk;
  __syncthreads();
  float rq = rsqrtf((red[0]+red[1]+red[2]+red[3]) / (float)QD + 1e-6f);
  float rk = rsqrtf((red[4]+red[5]+red[6]+red[7]) / (float)KD + 1e-6f);
  const float ascale = 0.08838834764831845f; // 1/sqrt(128), folded into Q
  for (int p = tid; p < 2048; p += 256) {
    int hh = p >> 6, i = p & 63;
    int i1 = hh*HD + i, i2 = i1 + 64;
    float x1 = (float)qrow[i1] * rq * qw[i1];
    float x2 = (float)qrow[i2] * rq * qw[i2];
    float sn = sc[(t*64 + i)*2 + 0], cs = sc[(t*64 + i)*2 + 1];
    qrow[i1] = (bf16_t)((x1*cs - x2*sn) * ascale);
    qrow[i2] = (bf16_t)((x2*cs + x1*sn) * ascale);
  }
  for (int p = tid; p < 512; p += 256) {
    int hh = p >> 6, i = p & 63;
    int i1 = hh*HD + i, i2 = i1 + 64;
    float x1 = (float)krow[i1] * rk * kw[i1];
    float x2 = (float)krow[i2] * rk * kw[i2];
    float sn = sc[(t*64 + i)*2 + 0], cs = sc[(t*64 + i)*2 + 1];
    krow[i1] = (bf16_t)(x1*cs - x2*sn);
    krow[i2] = (bf16_t)(x2*cs + x1*sn);
  }
}

// ---------------- flash attention, sliding window, GQA ----------------
// QB=128: 8 waves x 16 q rows, KV tile = 64 keys.
// Softmax redesigned to remove per-tile cross-lane reduce chains:
//  - max: lane-local 3-fmax + wave-uniform __any gate; full 16-lane reduce
//    + rescale ONLY on trigger (first tile, then rare) [defer-max T13].
//  - sum: per-lane partial lsum; single 16-lane reduce in the epilogue.
// T5 setprio around both MFMA clusters.
__global__ __launch_bounds__(512, 3) void attn_kernel(const bf16_t* __restrict__ qkv,
    const int* __restrict__ positions, const int* __restrict__ seg,
    bf16_t* __restrict__ O) {
  __shared__ bf16_t Ks[64 * HD];      // 16 KB, 16B-chunk XOR swizzle (linear dest, pre-swizzled src)
  __shared__ bf16_t Vt[HD * VS];      // 18 KB, V transposed [128 d][64 keys + pad]
  __shared__ bf16_t P[8][16 * VS];    // 18 KB, per-wave P tile
  int tid = threadIdx.x;
  int w = tid >> 6, l = tid & 63, lr = l & 15, lg = l >> 4;
  int qb = blockIdx.x * 128;
  int h = blockIdx.y;
  int kvh = h >> 2;
  int q0 = qb + w * 16;
  const bf16_t* Kg = qkv + QD + (size_t)kvh * HD;
  const bf16_t* Vg = qkv + QD + KD + (size_t)kvh * HD;

  bf16x8 qf[4];
  {
    const bf16_t* Qrow = qkv + (size_t)(q0 + lr) * QKVD + h * HD;
    #pragma unroll
    for (int c = 0; c < 4; c++) qf[c] = *(const bf16x8*)(Qrow + c*32 + lg*8);
  }
  int pos_i[4], seg_i[4];
  #pragma unroll
  for (int r = 0; r < 4; r++) { int i = q0 + lg*4 + r; pos_i[r] = positions[i]; seg_i[r] = seg[i]; }
  f32x4 o[8] = {};
  float m[4], lsum[4];
  #pragma unroll
  for (int r = 0; r < 4; r++) { m[r] = -__builtin_inff(); lsum[r] = 0.f; }

  // V item: key-pair + d-group (512 items, 1 per thread)
  int vkp = tid & 31, vdg = tid >> 5;
  bf16x8 vrA, vrB;

  // K staging: 1024 16B-chunks over 512 threads x 2
  auto issueK = [&](int j0) {
    #pragma unroll
    for (int i = 0; i < 2; i++) {
      int c = tid + i*512;
      int row = c >> 4;
      int scn = (c & 15) ^ (row & 7);
      gld_lds16(Kg + (size_t)(j0 + row) * QKVD + scn*8,
                (char*)Ks + (size_t)(i*512 + (tid & 448))*16);
    }
  };
  auto loadV = [&](int j0) {
    const bf16_t* vp = Vg + (size_t)(j0 + 2*vkp) * QKVD + vdg*8;
    vrA = *(const bf16x8*)vp;
    vrB = *(const bf16x8*)(vp + QKVD);
  };

  int jstart = qb - (WIN - 1); if (jstart < 0) jstart = 0; jstart &= ~63;
  const int jlast = qb + 64;   // covers rows up to qb+127
  loadV(jstart);
  issueK(jstart);

  for (int j0 = jstart; j0 <= jlast; j0 += 64) {
    // ---- Phase A: commit V(t); mask loads; prefetch V(t+1); drain K ----
    #pragma unroll
    for (int e = 0; e < 8; e++) {
      bf16x2 pr; pr[0] = vrA[e]; pr[1] = vrB[e];
      *(bf16x2*)(Vt + (vdg*8 + e)*VS + 2*vkp) = pr;
    }
    int pj[4], sj[4];
    #pragma unroll
    for (int kt = 0; kt < 4; kt++) { int j = j0 + kt*16 + lr; pj[kt] = positions[j]; sj[kt] = seg[j]; }
    asm volatile("" ::: "memory");
    if (j0 + 64 <= jlast) loadV(j0 + 64);
    asm volatile("" ::: "memory");
    asm volatile("s_waitcnt vmcnt(2) lgkmcnt(0)" ::: "memory");
    __builtin_amdgcn_s_barrier();

    // ---- Phase B: QK^T + softmax + P ----
    bool active = (j0 <= q0 + 15) && (j0 + 63 >= q0 - (WIN - 1));
    if (active) {
      f32x4 s[4] = {};
      __builtin_amdgcn_s_setprio(1);
      #pragma unroll
      for (int kt = 0; kt < 4; kt++) {
        int row = kt*16 + lr;
        const char* kb = (const char*)Ks + row*256;
        #pragma unroll
        for (int c = 0; c < 4; c++) {
          bf16x8 kf = *(const bf16x8*)(kb + (((c*4 + lg) ^ (row & 7)) * 16));
          s[kt] = __builtin_amdgcn_mfma_f32_16x16x32_bf16(qf[c], kf, s[kt], 0, 0, 0);
        }
      }
      __builtin_amdgcn_s_setprio(0);
      #pragma unroll
      for (int kt = 0; kt < 4; kt++) {
        #pragma unroll
        for (int r = 0; r < 4; r++) {
          bool valid = (pj[kt] <= pos_i[r]) && (pos_i[r] - pj[kt] < WIN) && (seg_i[r] == sj[kt]) && (sj[kt] != 0);
          s[kt][r] = valid ? s[kt][r] : -__builtin_inff();
        }
      }
      #pragma unroll
      for (int r = 0; r < 4; r++) {
        float smax = fmaxf(fmaxf(s[0][r], s[1][r]), fmaxf(s[2][r], s[3][r]));
        // wave-uniform gate: reduce+rescale only when some lane's local max
        // exceeds the running max by THR=8 (always on first active tile).
        if (__any(smax > m[r] + 8.f)) {
          float rm = smax;
          #pragma unroll
          for (int o2 = 1; o2 < 16; o2 <<= 1) rm = fmaxf(rm, __shfl_xor(rm, o2));
          if (rm > m[r] + 8.f) {
            float rescale = __expf(m[r] - rm);   // m=-inf -> 0
            lsum[r] *= rescale;
            #pragma unroll
            for (int n = 0; n < 8; n++) o[n][r] *= rescale;
            m[r] = rm;
          }
        }
        float mub = fmaxf(m[r], -1e37f);
        float p0 = __expf(s[0][r] - mub);
        float p1 = __expf(s[1][r] - mub);
        float p2 = __expf(s[2][r] - mub);
        float p3 = __expf(s[3][r] - mub);
        lsum[r] += (p0 + p1) + (p2 + p3);   // per-lane partial; reduced once at end
        int prow = (lg*4 + r) * VS;
        P[w][prow + lr]      = (bf16_t)p0;
        P[w][prow + 16 + lr] = (bf16_t)p1;
        P[w][prow + 32 + lr] = (bf16_t)p2;
        P[w][prow + 48 + lr] = (bf16_t)p3;
      }
    }
    __builtin_amdgcn_s_barrier();
    asm volatile("" ::: "memory");

    // ---- Phase C: issue K(t+1); PV ----
    if (j0 + 64 <= jlast) issueK(j0 + 64);
    if (active) {
      __builtin_amdgcn_s_setprio(1);
      #pragma unroll
      for (int ks = 0; ks < 2; ks++) {
        bf16x8 pa = *(const bf16x8*)(&P[w][lr*VS + ks*32 + lg*8]);
        #pragma unroll
        for (int n = 0; n < 8; n++) {
          bf16x8 vb = *(const bf16x8*)(&Vt[(n*16 + lr)*VS + ks*32 + lg*8]);
          o[n] = __builtin_amdgcn_mfma_f32_16x16x32_bf16(pa, vb, o[n], 0, 0, 0);
        }
      }
      __builtin_amdgcn_s_setprio(0);
    }
    __builtin_amdgcn_s_barrier();
  }
  #pragma unroll
  for (int r = 0; r < 4; r++) {
    float ls = lsum[r];
    #pragma unroll
    for (int o2 = 1; o2 < 16; o2 <<= 1) ls += __shfl_xor(ls, o2);
    float inv = ls > 0.f ? 1.f / ls : 0.f;
    int row = q0 + lg*4 + r;
    #pragma unroll
    for (int n = 0; n < 8; n++)
      O[(size_t)row * QD + h*HD + n*16 + lr] = (bf16_t)(o[n][r] * inv);
  }
}

// ---------------- launch ----------------
extern "C" void kernel_launch(void* const* d_in, const int* in_sizes, int n_in,
                              void* d_out, int out_size, void* d_ws, size_t ws_size,
                              hipStream_t stream) {
  (void)in_sizes; (void)n_in; (void)out_size; (void)ws_size;
  const float* x  = (const float*)d_in[0];
  const float* Wq = (const float*)d_in[1];
  const float* Wk = (const float*)d_in[2];
  const float* Wv = (const float*)d_in[3];
  const float* Wo = (const float*)d_in[4];
  const float* qw = (const float*)d_in[5];
  const float* kw = (const float*)d_in[6];
  const int*  seg = (const int*)d_in[7];
  float* out = (float*)d_out;

  char* base = (char*)d_ws;
  size_t off = 0;
  auto alloc = [&](size_t b) { void* r = base + off; off = (off + b + 255) & ~(size_t)255; return r; };
  bf16_t* xb    = (bf16_t*)alloc((size_t)T_LEN * DMODEL * 2);
  bf16_t* Wallt = (bf16_t*)alloc((size_t)QKVD * DMODEL * 2);
  bf16_t* Wot   = (bf16_t*)alloc((size_t)DMODEL * QD * 2);
  bf16_t* qkv   = (bf16_t*)alloc((size_t)T_LEN * QKVD * 2);
  int*    posi  = (int*)alloc((size_t)T_LEN * 4);
  float*  sc    = (float*)alloc((size_t)T_LEN * 64 * 2 * 4);
  bf16_t* ao    = xb;  // attention output aliases xb (xb dead after GEMM1)

  pos_kernel<<<1, 256, 0, stream>>>(seg, posi);
  sincos_kernel<<<T_LEN, 64, 0, stream>>>(posi, sc);
  cvt_kernel<<<(T_LEN * DMODEL / 8 + 255) / 256, 256, 0, stream>>>(x, xb, T_LEN * DMODEL);
  transcvt_kernel<<<dim3(QD/32, DMODEL/32), dim3(32, 8), 0, stream>>>(Wq, Wallt, DMODEL, QD);
  transcvt_kernel<<<dim3(KD/32, DMODEL/32), dim3(32, 8), 0, stream>>>(Wk, Wallt + (size_t)QD * DMODEL, DMODEL, KD);
  transcvt_kernel<<<dim3(KD/32, DMODEL/32), dim3(32, 8), 0, stream>>>(Wv, Wallt + (size_t)(QD + KD) * DMODEL, DMODEL, KD);
  transcvt_kernel<<<dim3(DMODEL/32, QD/32), dim3(32, 8), 0, stream>>>(Wo, Wot, QD, DMODEL);
  gemm256_kernel<true, 2><<<dim3((T_LEN/256)*(QKVD/256)), 512, 0, stream>>>(
      xb, Wallt, qkv, nullptr, T_LEN, QKVD, DMODEL, T_LEN/256);
  normrope_kernel<<<T_LEN, 256, 0, stream>>>(qkv, qw, kw, sc);
  attn_kernel<<<dim3(T_LEN/128, NHEADS), 512, 0, stream>>>(qkv, posi, seg, ao);
  gemm256_kernel<false, 1><<<dim3((T_LEN/128)*(DMODEL/256)), 512, 0, stream>>>(
      ao, Wot, nullptr, out, T_LEN, DMODEL, QD, T_LEN/128);
}

// Round 14
// 360.933 us; speedup vs baseline: 1.0814x; 1.0406x over previous
//
#include <hip/hip_runtime.h>
#include <cstdint>
#include <cstddef>

typedef __bf16 bf16_t;
typedef __bf16 bf16x8 __attribute__((ext_vector_type(8)));
typedef __bf16 bf16x4 __attribute__((ext_vector_type(4)));
typedef __bf16 bf16x2 __attribute__((ext_vector_type(2)));
typedef float f32x4 __attribute__((ext_vector_type(4)));

#define T_LEN 2048
#define DMODEL 4096
#define NHEADS 32
#define KVHEADS 8
#define HD 128
#define QD 4096   // NHEADS*HD
#define KD 1024   // KVHEADS*HD
#define QKVD 6144 // QD + 2*KD
#define WIN 1024
#define VS 72     // padded stride for attn Vt/P tiles (144B = 9*16B)

// ---------------- positions (argmax of segment row, first occurrence) ----------------
__global__ void pos_kernel(const int* __restrict__ seg, int* __restrict__ positions) {
  __shared__ int svals[256], sidx[256];
  int tid = threadIdx.x;
  int bestv = -2147483647 - 1, besti = 0;
  for (int t = tid; t < T_LEN; t += 256) {
    int v = seg[t];
    if (v > bestv) { bestv = v; besti = t; }
  }
  svals[tid] = bestv; sidx[tid] = besti;
  __syncthreads();
  for (int st = 128; st > 0; st >>= 1) {
    if (tid < st) {
      if (svals[tid+st] > svals[tid] || (svals[tid+st] == svals[tid] && sidx[tid+st] < sidx[tid])) {
        svals[tid] = svals[tid+st]; sidx[tid] = sidx[tid+st];
      }
    }
    __syncthreads();
  }
  int amax = sidx[0];
  for (int t = tid; t < T_LEN; t += 256)
    positions[t] = (seg[t] != 0) ? (t - amax) : (1 << 30);
}

// ---------------- rope sin/cos table ----------------
__global__ void sincos_kernel(const int* __restrict__ positions, float* __restrict__ sc) {
  int t = blockIdx.x, i = threadIdx.x; // 64 threads
  float inv = expf(-(float)i * (logf(500000.0f) / 64.0f));
  float ang = (float)positions[t] * inv;
  sc[(t*64 + i)*2 + 0] = sinf(ang);
  sc[(t*64 + i)*2 + 1] = cosf(ang);
}

// ---------------- f32 -> bf16 convert (8/thread) ----------------
__global__ void cvt_kernel(const float* __restrict__ in, bf16_t* __restrict__ out, int n) {
  int i = (blockIdx.x * blockDim.x + threadIdx.x) * 8;
  if (i >= n) return;
  float4 a = *(const float4*)(in + i);
  float4 b = *(const float4*)(in + i + 4);
  bf16x8 o;
  o[0]=(bf16_t)a.x; o[1]=(bf16_t)a.y; o[2]=(bf16_t)a.z; o[3]=(bf16_t)a.w;
  o[4]=(bf16_t)b.x; o[5]=(bf16_t)b.y; o[6]=(bf16_t)b.z; o[7]=(bf16_t)b.w;
  *(bf16x8*)(out + i) = o;
}

// ---------------- transpose + convert: W[K][N] f32 -> Wt[N][K] bf16 ----------------
__global__ void transcvt_kernel(const float* __restrict__ W, bf16_t* __restrict__ Wt, int K, int N) {
  __shared__ float tile[32][33];
  int tx = threadIdx.x, ty = threadIdx.y; // 32 x 8
  int bx = blockIdx.x, by = blockIdx.y;
  #pragma unroll
  for (int i = 0; i < 4; i++) {
    int k = by*32 + ty + i*8;
    tile[ty + i*8][tx] = W[(size_t)k * N + bx*32 + tx];
  }
  __syncthreads();
  int t = ty*32 + tx;
  int n = t >> 3;
  int kq = t & 7;
  bf16x4 v;
  #pragma unroll
  for (int e = 0; e < 4; e++) v[e] = (bf16_t)tile[kq*4 + e][n];
  *(bf16x4*)(Wt + (size_t)(bx*32 + n) * K + by*32 + kq*4) = v;
}

__device__ __forceinline__ void gld_lds16(const void* g, void* l) {
  __builtin_amdgcn_global_load_lds((__attribute__((address_space(1))) void*)g,
                                   (__attribute__((address_space(3))) void*)l, 16, 0, 0);
}

// ---------------- GEMM1: 256x192 tile, 8 waves (2Mx4N), per-wave 128x48, bf16 out ----------------
// Grid 8x32 = 256 blocks = exact CU fill (vs 192 blocks @256x256 = 25% idle).
// B staged as 3x 64-row units (1 gld/thread), A as 2x 128-row units (2 gld/thread).
// 7 loads/tile; steady-state outstanding 7(t+1)+6(t+2) -> vmcnt(6) retires t+1.
__global__ __launch_bounds__(512, 2) void gemm192_kernel(
    const bf16_t* __restrict__ A, const bf16_t* __restrict__ Bt,
    bf16_t* __restrict__ Cb, int M, int N, int K, int NBM) {
  __shared__ bf16_t As[2 * 256 * 64];   // 64 KB
  __shared__ bf16_t Bs[2 * 192 * 64];   // 48 KB
  int tid = threadIdx.x;
  int w = tid >> 6, l = tid & 63, lr = l & 15, lg = l >> 4;
  int wr = w >> 2, wc = w & 3;
  int nwg = gridDim.x;
  int wg  = blockIdx.x;
  int cpx = nwg >> 3;
  int swz = (wg & 7) * cpx + (wg >> 3);
  int bm = swz % NBM, bn = swz / NBM;
  const int NT = K >> 6;

  auto stageA = [&](int tt, int h) {   // h=0,1 : rows h*128..+127, 2 loads
    int b2 = tt & 1;
    bf16_t* ldsb = As + b2*16384 + h*8192;
    #pragma unroll
    for (int r2 = 0; r2 < 2; r2++) {
      int L = r2*8192 + tid*16;
      int row = L >> 7;
      int chunk = (L >> 4) & 7;
      int scn = chunk ^ (row & 7);
      gld_lds16(A + ((size_t)bm*256 + h*128 + row) * K + tt*64 + scn*8,
                ldsb + r2*4096 + w*512);
    }
  };
  auto stageB = [&](int tt, int u) {   // u=0..2 : rows u*64..+63, 1 load
    int b2 = tt & 1;
    bf16_t* ldsb = Bs + b2*12288 + u*4096;
    int row = tid >> 3;
    int scn = (tid & 7) ^ (row & 7);
    gld_lds16(Bt + ((size_t)bn*192 + u*64 + row) * K + tt*64 + scn*8,
              ldsb + w*512);
  };
  auto afrag = [&](int b2, int row, int kk) -> bf16x8 {
    int chunk = (kk*4 + lg) ^ (row & 7);
    return *(const bf16x8*)((const char*)(As + b2*16384) + row*128 + chunk*16);
  };
  auto bfrag = [&](int b2, int row, int kk) -> bf16x8 {
    int chunk = (kk*4 + lg) ^ (row & 7);
    return *(const bf16x8*)((const char*)(Bs + b2*12288) + row*128 + chunk*16);
  };

  f32x4 acc[8][3] = {};
  bf16x8 a[8][2], bb[3][2];

  // prologue: tile0 complete (7), tile1 A0,A1,B0,B1 (6)
  stageA(0, 0); stageA(0, 1); stageB(0, 0); stageB(0, 1); stageB(0, 2);
  stageA(1, 0); stageA(1, 1); stageB(1, 0); stageB(1, 1);
  asm volatile("s_waitcnt vmcnt(6)" ::: "memory");
  __builtin_amdgcn_s_barrier();

  for (int t = 0; t < NT; t++) {
    int b = t & 1;
    // ---- ph1: read all A + B fn0,1; stage(t+1,B2); MFMA fm0-3 x fn0-1
    #pragma unroll
    for (int fm = 0; fm < 8; fm++)
      #pragma unroll
      for (int kk = 0; kk < 2; kk++)
        a[fm][kk] = afrag(b, wr*128 + fm*16 + lr, kk);
    #pragma unroll
    for (int fn = 0; fn < 2; fn++)
      #pragma unroll
      for (int kk = 0; kk < 2; kk++)
        bb[fn][kk] = bfrag(b, wc*48 + fn*16 + lr, kk);
    if (t + 1 < NT) stageB(t + 1, 2);
    __builtin_amdgcn_s_barrier();
    asm volatile("s_waitcnt lgkmcnt(0)" ::: "memory");
    __builtin_amdgcn_s_setprio(1);
    #pragma unroll
    for (int fm = 0; fm < 4; fm++)
      #pragma unroll
      for (int fn = 0; fn < 2; fn++)
        #pragma unroll
        for (int kk = 0; kk < 2; kk++)
          acc[fm][fn] = __builtin_amdgcn_mfma_f32_16x16x32_bf16(a[fm][kk], bb[fn][kk], acc[fm][fn], 0, 0, 0);
    __builtin_amdgcn_s_setprio(0);
    __builtin_amdgcn_s_barrier();
    // ---- ph2: read B fn2; stage(t+2,A0); MFMA fm0-3 x fn2
    #pragma unroll
    for (int kk = 0; kk < 2; kk++)
      bb[2][kk] = bfrag(b, wc*48 + 32 + lr, kk);
    if (t + 2 < NT) stageA(t + 2, 0);
    __builtin_amdgcn_s_barrier();
    asm volatile("s_waitcnt lgkmcnt(0)" ::: "memory");
    __builtin_amdgcn_s_setprio(1);
    #pragma unroll
    for (int fm = 0; fm < 4; fm++)
      #pragma unroll
      for (int kk = 0; kk < 2; kk++)
        acc[fm][2] = __builtin_amdgcn_mfma_f32_16x16x32_bf16(a[fm][kk], bb[2][kk], acc[fm][2], 0, 0, 0);
    __builtin_amdgcn_s_setprio(0);
    __builtin_amdgcn_s_barrier();
    // ---- ph3: stage(t+2,A1); MFMA fm4-7 x fn2
    if (t + 2 < NT) stageA(t + 2, 1);
    __builtin_amdgcn_s_barrier();
    __builtin_amdgcn_s_setprio(1);
    #pragma unroll
    for (int fm = 4; fm < 8; fm++)
      #pragma unroll
      for (int kk = 0; kk < 2; kk++)
        acc[fm][2] = __builtin_amdgcn_mfma_f32_16x16x32_bf16(a[fm][kk], bb[2][kk], acc[fm][2], 0, 0, 0);
    __builtin_amdgcn_s_setprio(0);
    __builtin_amdgcn_s_barrier();
    // ---- ph4: stage(t+2,B0,B1); MFMA fm4-7 x fn0-1; counted vmcnt
    if (t + 2 < NT) { stageB(t + 2, 0); stageB(t + 2, 1); }
    __builtin_amdgcn_s_barrier();
    __builtin_amdgcn_s_setprio(1);
    #pragma unroll
    for (int fm = 4; fm < 8; fm++)
      #pragma unroll
      for (int fn = 0; fn < 2; fn++)
        #pragma unroll
        for (int kk = 0; kk < 2; kk++)
          acc[fm][fn] = __builtin_amdgcn_mfma_f32_16x16x32_bf16(a[fm][kk], bb[fn][kk], acc[fm][fn], 0, 0, 0);
    __builtin_amdgcn_s_setprio(0);
    if (t < NT - 2) asm volatile("s_waitcnt vmcnt(6)" ::: "memory");
    else            asm volatile("s_waitcnt vmcnt(0)" ::: "memory");
    __builtin_amdgcn_s_barrier();
  }

  #pragma unroll
  for (int fm = 0; fm < 8; fm++) {
    #pragma unroll
    for (int fn = 0; fn < 3; fn++) {
      #pragma unroll
      for (int r2 = 0; r2 < 4; r2++) {
        int row = bm*256 + wr*128 + fm*16 + lg*4 + r2;
        int col = bn*192 + wc*48 + fn*16 + lr;
        Cb[(size_t)row * N + col] = (bf16_t)acc[fm][fn][r2];
      }
    }
  }
}

// ---------------- GEMM2: 8-phase AM=1 (128x256), f32 out (unchanged, R9-proven) ----------------
#define MFMA_QUAD(FM0, FN0)                                                     \
  { _Pragma("unroll") for (int fm_ = 0; fm_ < QFM; fm_++)                        \
    _Pragma("unroll") for (int fn_ = 0; fn_ < 2; fn_++)                          \
    _Pragma("unroll") for (int kk_ = 0; kk_ < 2; kk_++)                          \
      acc[(FM0)+fm_][(FN0)+fn_] = __builtin_amdgcn_mfma_f32_16x16x32_bf16(       \
          a[(FM0)+fm_][kk_], bb[(FN0)+fn_][kk_], acc[(FM0)+fm_][(FN0)+fn_], 0,0,0); }

template<bool WRITE_BF16, int AM>
__global__ __launch_bounds__(512, 2) void gemm256_kernel(
    const bf16_t* __restrict__ A, const bf16_t* __restrict__ Bt,
    bf16_t* __restrict__ Cb, float* __restrict__ Cf,
    int M, int N, int K, int NBM) {
  constexpr int BM  = AM * 128;
  constexpr int NH  = AM + 2;
  constexpr int FM2 = AM * 4;
  constexpr int QFM = AM * 2;
  __shared__ bf16_t As[2 * BM * 64];
  __shared__ bf16_t Bs[2 * 256 * 64];
  int tid = threadIdx.x;
  int w = tid >> 6, l = tid & 63, lr = l & 15, lg = l >> 4;
  int wr = w >> 2, wc = w & 3;
  int nwg = gridDim.x;
  int wg  = blockIdx.x;
  int cpx = nwg >> 3;
  int swz = (wg & 7) * cpx + (wg >> 3);
  int bm = swz % NBM, bn = swz / NBM;
  const int NT = K >> 6;

  auto stage = [&](int tt, int h) {
    int b2 = tt & 1;
    const bf16_t* G; size_t grow0; bf16_t* ldsb;
    if (h < AM) { G = A;  grow0 = (size_t)bm*BM + h*128;        ldsb = As + b2*(BM*64) + h*8192; }
    else        { G = Bt; grow0 = (size_t)bn*256 + (h-AM)*128;  ldsb = Bs + b2*16384 + (h-AM)*8192; }
    int kcol = tt * 64;
    #pragma unroll
    for (int r2 = 0; r2 < 2; r2++) {
      int L = r2*8192 + tid*16;
      int row = L >> 7;
      int chunk = (L >> 4) & 7;
      int scn = chunk ^ (row & 7);
      gld_lds16(G + (grow0 + (size_t)row) * K + kcol + scn*8,
                ldsb + r2*4096 + w*512);
    }
  };
  auto afrag = [&](int b2, int row, int kk) -> bf16x8 {
    int chunk = (kk*4 + lg) ^ (row & 7);
    return *(const bf16x8*)((const char*)(As + b2*(BM*64)) + row*128 + chunk*16);
  };
  auto bfrag = [&](int b2, int row, int kk) -> bf16x8 {
    int chunk = (kk*4 + lg) ^ (row & 7);
    return *(const bf16x8*)((const char*)(Bs + b2*16384) + row*128 + chunk*16);
  };

  f32x4 acc[FM2][4] = {};
  bf16x8 a[FM2][2], bb[4][2];

  #pragma unroll
  for (int h = 0; h < NH; h++) stage(0, h);
  #pragma unroll
  for (int h = 0; h < NH - 1; h++) stage(1, h);
  if constexpr (AM == 2) asm volatile("s_waitcnt vmcnt(6)" ::: "memory");
  else                   asm volatile("s_waitcnt vmcnt(4)" ::: "memory");
  __builtin_amdgcn_s_barrier();

  for (int t = 0; t < NT; t++) {
    int b = t & 1;
    #pragma unroll
    for (int fm = 0; fm < FM2; fm++)
      #pragma unroll
      for (int kk = 0; kk < 2; kk++)
        a[fm][kk] = afrag(b, wr*(BM/2) + fm*16 + lr, kk);
    #pragma unroll
    for (int fn = 0; fn < 2; fn++)
      #pragma unroll
      for (int kk = 0; kk < 2; kk++)
        bb[fn][kk] = bfrag(b, wc*64 + fn*16 + lr, kk);
    if (t + 1 < NT) stage(t + 1, NH - 1);
    __builtin_amdgcn_s_barrier();
    asm volatile("s_waitcnt lgkmcnt(0)" ::: "memory");
    __builtin_amdgcn_s_setprio(1);
    MFMA_QUAD(0, 0);
    __builtin_amdgcn_s_setprio(0);
    __builtin_amdgcn_s_barrier();
    #pragma unroll
    for (int fn = 2; fn < 4; fn++)
      #pragma unroll
      for (int kk = 0; kk < 2; kk++)
        bb[fn][kk] = bfrag(b, wc*64 + fn*16 + lr, kk);
    if (t + 2 < NT) stage(t + 2, 0);
    __builtin_amdgcn_s_barrier();
    asm volatile("s_waitcnt lgkmcnt(0)" ::: "memory");
    __builtin_amdgcn_s_setprio(1);
    MFMA_QUAD(0, 2);
    __builtin_amdgcn_s_setprio(0);
    __builtin_amdgcn_s_barrier();
    if (t + 2 < NT) stage(t + 2, 1);
    __builtin_amdgcn_s_barrier();
    __builtin_amdgcn_s_setprio(1);
    MFMA_QUAD(QFM, 2);
    __builtin_amdgcn_s_setprio(0);
    __builtin_amdgcn_s_barrier();
    if constexpr (AM == 2) { if (t + 2 < NT) stage(t + 2, 2); }
    __builtin_amdgcn_s_barrier();
    __builtin_amdgcn_s_setprio(1);
    MFMA_QUAD(QFM, 0);
    __builtin_amdgcn_s_setprio(0);
    if (t < NT - 2) {
      if constexpr (AM == 2) asm volatile("s_waitcnt vmcnt(6)" ::: "memory");
      else                   asm volatile("s_waitcnt vmcnt(4)" ::: "memory");
    } else {
      asm volatile("s_waitcnt vmcnt(0)" ::: "memory");
    }
    __builtin_amdgcn_s_barrier();
  }

  #pragma unroll
  for (int fm = 0; fm < FM2; fm++) {
    #pragma unroll
    for (int fn = 0; fn < 4; fn++) {
      #pragma unroll
      for (int r2 = 0; r2 < 4; r2++) {
        int row = bm*BM + wr*(BM/2) + fm*16 + lg*4 + r2;
        int col = bn*256 + wc*64 + fn*16 + lr;
        if (WRITE_BF16) Cb[(size_t)row * N + col] = (bf16_t)acc[fm][fn][r2];
        else            Cf[(size_t)row * N + col] = acc[fm][fn][r2];
      }
    }
  }
}

// ---------------- fused RMSNorm + RoPE + q-scale ----------------
__global__ __launch_bounds__(256) void normrope_kernel(bf16_t* __restrict__ qkv,
    const float* __restrict__ qw, const float* __restrict__ kw,
    const float* __restrict__ sc) {
  int t = blockIdx.x;
  int tid = threadIdx.x;
  bf16_t* qrow = qkv + (size_t)t * QKVD;
  bf16_t* krow = qrow + QD;
  __shared__ float red[8];
  float s = 0.f;
  {
    const bf16x8* p = (const bf16x8*)(qrow + tid*16);
    bf16x8 v0 = p[0], v1 = p[1];
    #pragma unroll
    for (int j = 0; j < 8; j++) { float a = (float)v0[j], b = (float)v1[j]; s += a*a + b*b; }
  }
  #pragma unroll
  for (int o = 32; o; o >>= 1) s += __shfl_xor(s, o);
  if ((tid & 63) == 0) red[tid >> 6] = s;
  float sk = 0.f;
  {
    bf16x4 v = *(const bf16x4*)(krow + tid*4);
    #pragma unroll
    for (int j = 0; j < 4; j++) { float a = (float)v[j]; sk += a*a; }
  }
  #pragma unroll
  for (int o = 32; o; o >>= 1) sk += __shfl_xor(sk, o);
  if ((tid & 63) == 0) red[4 + (tid >> 6)] = sk;
  __syncthreads();
  float rq = rsqrtf((red[0]+red[1]+red[2]+red[3]) / (float)QD + 1e-6f);
  float rk = rsqrtf((red[4]+red[5]+red[6]+red[7]) / (float)KD + 1e-6f);
  const float ascale = 0.08838834764831845f;
  for (int p = tid; p < 2048; p += 256) {
    int hh = p >> 6, i = p & 63;
    int i1 = hh*HD + i, i2 = i1 + 64;
    float x1 = (float)qrow[i1] * rq * qw[i1];
    float x2 = (float)qrow[i2] * rq * qw[i2];
    float sn = sc[(t*64 + i)*2 + 0], cs = sc[(t*64 + i)*2 + 1];
    qrow[i1] = (bf16_t)((x1*cs - x2*sn) * ascale);
    qrow[i2] = (bf16_t)((x2*cs + x1*sn) * ascale);
  }
  for (int p = tid; p < 512; p += 256) {
    int hh = p >> 6, i = p & 63;
    int i1 = hh*HD + i, i2 = i1 + 64;
    float x1 = (float)krow[i1] * rk * kw[i1];
    float x2 = (float)krow[i2] * rk * kw[i2];
    float sn = sc[(t*64 + i)*2 + 0], cs = sc[(t*64 + i)*2 + 1];
    krow[i1] = (bf16_t)(x1*cs - x2*sn);
    krow[i2] = (bf16_t)(x2*cs + x1*sn);
  }
}

// ---------------- flash attention (R13 version, unchanged) ----------------
__global__ __launch_bounds__(512, 3) void attn_kernel(const bf16_t* __restrict__ qkv,
    const int* __restrict__ positions, const int* __restrict__ seg,
    bf16_t* __restrict__ O) {
  __shared__ bf16_t Ks[64 * HD];
  __shared__ bf16_t Vt[HD * VS];
  __shared__ bf16_t P[8][16 * VS];
  int tid = threadIdx.x;
  int w = tid >> 6, l = tid & 63, lr = l & 15, lg = l >> 4;
  int qb = blockIdx.x * 128;
  int h = blockIdx.y;
  int kvh = h >> 2;
  int q0 = qb + w * 16;
  const bf16_t* Kg = qkv + QD + (size_t)kvh * HD;
  const bf16_t* Vg = qkv + QD + KD + (size_t)kvh * HD;

  bf16x8 qf[4];
  {
    const bf16_t* Qrow = qkv + (size_t)(q0 + lr) * QKVD + h * HD;
    #pragma unroll
    for (int c = 0; c < 4; c++) qf[c] = *(const bf16x8*)(Qrow + c*32 + lg*8);
  }
  int pos_i[4], seg_i[4];
  #pragma unroll
  for (int r = 0; r < 4; r++) { int i = q0 + lg*4 + r; pos_i[r] = positions[i]; seg_i[r] = seg[i]; }
  f32x4 o[8] = {};
  float m[4], lsum[4];
  #pragma unroll
  for (int r = 0; r < 4; r++) { m[r] = -__builtin_inff(); lsum[r] = 0.f; }

  int vkp = tid & 31, vdg = tid >> 5;
  bf16x8 vrA, vrB;

  auto issueK = [&](int j0) {
    #pragma unroll
    for (int i = 0; i < 2; i++) {
      int c = tid + i*512;
      int row = c >> 4;
      int scn = (c & 15) ^ (row & 7);
      gld_lds16(Kg + (size_t)(j0 + row) * QKVD + scn*8,
                (char*)Ks + (size_t)(i*512 + (tid & 448))*16);
    }
  };
  auto loadV = [&](int j0) {
    const bf16_t* vp = Vg + (size_t)(j0 + 2*vkp) * QKVD + vdg*8;
    vrA = *(const bf16x8*)vp;
    vrB = *(const bf16x8*)(vp + QKVD);
  };

  int jstart = qb - (WIN - 1); if (jstart < 0) jstart = 0; jstart &= ~63;
  const int jlast = qb + 64;
  loadV(jstart);
  issueK(jstart);

  for (int j0 = jstart; j0 <= jlast; j0 += 64) {
    #pragma unroll
    for (int e = 0; e < 8; e++) {
      bf16x2 pr; pr[0] = vrA[e]; pr[1] = vrB[e];
      *(bf16x2*)(Vt + (vdg*8 + e)*VS + 2*vkp) = pr;
    }
    int pj[4], sj[4];
    #pragma unroll
    for (int kt = 0; kt < 4; kt++) { int j = j0 + kt*16 + lr; pj[kt] = positions[j]; sj[kt] = seg[j]; }
    asm volatile("" ::: "memory");
    if (j0 + 64 <= jlast) loadV(j0 + 64);
    asm volatile("" ::: "memory");
    asm volatile("s_waitcnt vmcnt(2) lgkmcnt(0)" ::: "memory");
    __builtin_amdgcn_s_barrier();

    bool active = (j0 <= q0 + 15) && (j0 + 63 >= q0 - (WIN - 1));
    if (active) {
      f32x4 s[4] = {};
      __builtin_amdgcn_s_setprio(1);
      #pragma unroll
      for (int kt = 0; kt < 4; kt++) {
        int row = kt*16 + lr;
        const char* kb = (const char*)Ks + row*256;
        #pragma unroll
        for (int c = 0; c < 4; c++) {
          bf16x8 kf = *(const bf16x8*)(kb + (((c*4 + lg) ^ (row & 7)) * 16));
          s[kt] = __builtin_amdgcn_mfma_f32_16x16x32_bf16(qf[c], kf, s[kt], 0, 0, 0);
        }
      }
      __builtin_amdgcn_s_setprio(0);
      #pragma unroll
      for (int kt = 0; kt < 4; kt++) {
        #pragma unroll
        for (int r = 0; r < 4; r++) {
          bool valid = (pj[kt] <= pos_i[r]) && (pos_i[r] - pj[kt] < WIN) && (seg_i[r] == sj[kt]) && (sj[kt] != 0);
          s[kt][r] = valid ? s[kt][r] : -__builtin_inff();
        }
      }
      #pragma unroll
      for (int r = 0; r < 4; r++) {
        float smax = fmaxf(fmaxf(s[0][r], s[1][r]), fmaxf(s[2][r], s[3][r]));
        if (__any(smax > m[r] + 8.f)) {
          float rm = smax;
          #pragma unroll
          for (int o2 = 1; o2 < 16; o2 <<= 1) rm = fmaxf(rm, __shfl_xor(rm, o2));
          if (rm > m[r] + 8.f) {
            float rescale = __expf(m[r] - rm);
            lsum[r] *= rescale;
            #pragma unroll
            for (int n = 0; n < 8; n++) o[n][r] *= rescale;
            m[r] = rm;
          }
        }
        float mub = fmaxf(m[r], -1e37f);
        float p0 = __expf(s[0][r] - mub);
        float p1 = __expf(s[1][r] - mub);
        float p2 = __expf(s[2][r] - mub);
        float p3 = __expf(s[3][r] - mub);
        lsum[r] += (p0 + p1) + (p2 + p3);
        int prow = (lg*4 + r) * VS;
        P[w][prow + lr]      = (bf16_t)p0;
        P[w][prow + 16 + lr] = (bf16_t)p1;
        P[w][prow + 32 + lr] = (bf16_t)p2;
        P[w][prow + 48 + lr] = (bf16_t)p3;
      }
    }
    __builtin_amdgcn_s_barrier();
    asm volatile("" ::: "memory");

    if (j0 + 64 <= jlast) issueK(j0 + 64);
    if (active) {
      __builtin_amdgcn_s_setprio(1);
      #pragma unroll
      for (int ks = 0; ks < 2; ks++) {
        bf16x8 pa = *(const bf16x8*)(&P[w][lr*VS + ks*32 + lg*8]);
        #pragma unroll
        for (int n = 0; n < 8; n++) {
          bf16x8 vb = *(const bf16x8*)(&Vt[(n*16 + lr)*VS + ks*32 + lg*8]);
          o[n] = __builtin_amdgcn_mfma_f32_16x16x32_bf16(pa, vb, o[n], 0, 0, 0);
        }
      }
      __builtin_amdgcn_s_setprio(0);
    }
    __builtin_amdgcn_s_barrier();
  }
  #pragma unroll
  for (int r = 0; r < 4; r++) {
    float ls = lsum[r];
    #pragma unroll
    for (int o2 = 1; o2 < 16; o2 <<= 1) ls += __shfl_xor(ls, o2);
    float inv = ls > 0.f ? 1.f / ls : 0.f;
    int row = q0 + lg*4 + r;
    #pragma unroll
    for (int n = 0; n < 8; n++)
      O[(size_t)row * QD + h*HD + n*16 + lr] = (bf16_t)(o[n][r] * inv);
  }
}

// ---------------- launch ----------------
extern "C" void kernel_launch(void* const* d_in, const int* in_sizes, int n_in,
                              void* d_out, int out_size, void* d_ws, size_t ws_size,
                              hipStream_t stream) {
  (void)in_sizes; (void)n_in; (void)out_size; (void)ws_size;
  const float* x  = (const float*)d_in[0];
  const float* Wq = (const float*)d_in[1];
  const float* Wk = (const float*)d_in[2];
  const float* Wv = (const float*)d_in[3];
  const float* Wo = (const float*)d_in[4];
  const float* qw = (const float*)d_in[5];
  const float* kw = (const float*)d_in[6];
  const int*  seg = (const int*)d_in[7];
  float* out = (float*)d_out;

  char* base = (char*)d_ws;
  size_t off = 0;
  auto alloc = [&](size_t b) { void* r = base + off; off = (off + b + 255) & ~(size_t)255; return r; };
  bf16_t* xb    = (bf16_t*)alloc((size_t)T_LEN * DMODEL * 2);
  bf16_t* Wallt = (bf16_t*)alloc((size_t)QKVD * DMODEL * 2);
  bf16_t* Wot   = (bf16_t*)alloc((size_t)DMODEL * QD * 2);
  bf16_t* qkv   = (bf16_t*)alloc((size_t)T_LEN * QKVD * 2);
  int*    posi  = (int*)alloc((size_t)T_LEN * 4);
  float*  sc    = (float*)alloc((size_t)T_LEN * 64 * 2 * 4);
  bf16_t* ao    = xb;  // attention output aliases xb (xb dead after GEMM1)

  pos_kernel<<<1, 256, 0, stream>>>(seg, posi);
  sincos_kernel<<<T_LEN, 64, 0, stream>>>(posi, sc);
  cvt_kernel<<<(T_LEN * DMODEL / 8 + 255) / 256, 256, 0, stream>>>(x, xb, T_LEN * DMODEL);
  transcvt_kernel<<<dim3(QD/32, DMODEL/32), dim3(32, 8), 0, stream>>>(Wq, Wallt, DMODEL, QD);
  transcvt_kernel<<<dim3(KD/32, DMODEL/32), dim3(32, 8), 0, stream>>>(Wk, Wallt + (size_t)QD * DMODEL, DMODEL, KD);
  transcvt_kernel<<<dim3(KD/32, DMODEL/32), dim3(32, 8), 0, stream>>>(Wv, Wallt + (size_t)(QD + KD) * DMODEL, DMODEL, KD);
  transcvt_kernel<<<dim3(DMODEL/32, QD/32), dim3(32, 8), 0, stream>>>(Wo, Wot, QD, DMODEL);
  // GEMM1: 256x192 tiles -> 8 x 32 = 256 blocks (exact CU fill)
  gemm192_kernel<<<dim3((T_LEN/256)*(QKVD/192)), 512, 0, stream>>>(
      xb, Wallt, qkv, T_LEN, QKVD, DMODEL, T_LEN/256);
  normrope_kernel<<<T_LEN, 256, 0, stream>>>(qkv, qw, kw, sc);
  attn_kernel<<<dim3(T_LEN/128, NHEADS), 512, 0, stream>>>(qkv, posi, seg, ao);
  gemm256_kernel<false, 1><<<dim3((T_LEN/128)*(DMODEL/256)), 512, 0, stream>>>(
      ao, Wot, nullptr, out, T_LEN, DMODEL, QD, T_LEN/128);
}

// Round 15
// 358.549 us; speedup vs baseline: 1.0886x; 1.0066x over previous
//
#include <hip/hip_runtime.h>
#include <cstdint>
#include <cstddef>

typedef __bf16 bf16_t;
typedef __bf16 bf16x8 __attribute__((ext_vector_type(8)));
typedef __bf16 bf16x4 __attribute__((ext_vector_type(4)));
typedef __bf16 bf16x2 __attribute__((ext_vector_type(2)));
typedef float f32x4 __attribute__((ext_vector_type(4)));

#define T_LEN 2048
#define DMODEL 4096
#define NHEADS 32
#define KVHEADS 8
#define HD 128
#define QD 4096   // NHEADS*HD
#define KD 1024   // KVHEADS*HD
#define QKVD 6144 // QD + 2*KD
#define WIN 1024
#define VS 72     // padded stride for attn Vt/P tiles (144B = 9*16B)

// ---------------- positions (argmax of segment row, first occurrence) ----------------
__global__ void pos_kernel(const int* __restrict__ seg, int* __restrict__ positions) {
  __shared__ int svals[256], sidx[256];
  int tid = threadIdx.x;
  int bestv = -2147483647 - 1, besti = 0;
  for (int t = tid; t < T_LEN; t += 256) {
    int v = seg[t];
    if (v > bestv) { bestv = v; besti = t; }
  }
  svals[tid] = bestv; sidx[tid] = besti;
  __syncthreads();
  for (int st = 128; st > 0; st >>= 1) {
    if (tid < st) {
      if (svals[tid+st] > svals[tid] || (svals[tid+st] == svals[tid] && sidx[tid+st] < sidx[tid])) {
        svals[tid] = svals[tid+st]; sidx[tid] = sidx[tid+st];
      }
    }
    __syncthreads();
  }
  int amax = sidx[0];
  for (int t = tid; t < T_LEN; t += 256)
    positions[t] = (seg[t] != 0) ? (t - amax) : (1 << 30);
}

// ---------------- rope sin/cos table ----------------
__global__ void sincos_kernel(const int* __restrict__ positions, float* __restrict__ sc) {
  int t = blockIdx.x, i = threadIdx.x; // 64 threads
  float inv = expf(-(float)i * (logf(500000.0f) / 64.0f));
  float ang = (float)positions[t] * inv;
  sc[(t*64 + i)*2 + 0] = sinf(ang);
  sc[(t*64 + i)*2 + 1] = cosf(ang);
}

// ---------------- f32 -> bf16 convert (8/thread) ----------------
__global__ void cvt_kernel(const float* __restrict__ in, bf16_t* __restrict__ out, int n) {
  int i = (blockIdx.x * blockDim.x + threadIdx.x) * 8;
  if (i >= n) return;
  float4 a = *(const float4*)(in + i);
  float4 b = *(const float4*)(in + i + 4);
  bf16x8 o;
  o[0]=(bf16_t)a.x; o[1]=(bf16_t)a.y; o[2]=(bf16_t)a.z; o[3]=(bf16_t)a.w;
  o[4]=(bf16_t)b.x; o[5]=(bf16_t)b.y; o[6]=(bf16_t)b.z; o[7]=(bf16_t)b.w;
  *(bf16x8*)(out + i) = o;
}

// ---------------- transpose + convert: W[K][N] f32 -> Wt[N][K] bf16 ----------------
__global__ void transcvt_kernel(const float* __restrict__ W, bf16_t* __restrict__ Wt, int K, int N) {
  __shared__ float tile[32][33];
  int tx = threadIdx.x, ty = threadIdx.y; // 32 x 8
  int bx = blockIdx.x, by = blockIdx.y;
  #pragma unroll
  for (int i = 0; i < 4; i++) {
    int k = by*32 + ty + i*8;
    tile[ty + i*8][tx] = W[(size_t)k * N + bx*32 + tx];
  }
  __syncthreads();
  int t = ty*32 + tx;
  int n = t >> 3;
  int kq = t & 7;
  bf16x4 v;
  #pragma unroll
  for (int e = 0; e < 4; e++) v[e] = (bf16_t)tile[kq*4 + e][n];
  *(bf16x4*)(Wt + (size_t)(bx*32 + n) * K + by*32 + kq*4) = v;
}

__device__ __forceinline__ void gld_lds16(const void* g, void* l) {
  __builtin_amdgcn_global_load_lds((__attribute__((address_space(1))) void*)g,
                                   (__attribute__((address_space(3))) void*)l, 16, 0, 0);
}

// ---------------- GEMM1: 128x192 tile, 8 waves (2Mx4N), wave 64x48, 2 blocks/CU ----------------
// Grid 16x32 = 512 blocks (full fill, 2/CU via 80KB LDS -> barrier stalls hidden
// by the co-resident block). 5 staging units/tile (A:2, B:3), 1 gld/thread each.
// Steady queue 4->5->7->9; vmcnt(4) retires tile t+1. Stage-after-lgkm-barrier
// invariant preserved for every unit (B units read through ph3 -> staged in ph4).
__global__ __launch_bounds__(512, 2) void gemm1_kernel(
    const bf16_t* __restrict__ A, const bf16_t* __restrict__ Bt,
    bf16_t* __restrict__ Cb, int M, int N, int K, int NBM) {
  __shared__ bf16_t As[2 * 128 * 64];   // 32 KB
  __shared__ bf16_t Bs[2 * 192 * 64];   // 48 KB
  int tid = threadIdx.x;
  int w = tid >> 6, l = tid & 63, lr = l & 15, lg = l >> 4;
  int wr = w >> 2, wc = w & 3;
  int nwg = gridDim.x;
  int wg  = blockIdx.x;
  int cpx = nwg >> 3;
  int swz = (wg & 7) * cpx + (wg >> 3);
  int bm = swz % NBM, bn = swz / NBM;
  const int NT = K >> 6;

  auto stageA = [&](int tt, int h) {   // h=0,1 : rows h*64..+63, 1 load/thread
    bf16_t* ldsb = As + (tt & 1)*8192 + h*4096;
    int row = tid >> 3;
    int scn = (tid & 7) ^ (row & 7);
    gld_lds16(A + ((size_t)bm*128 + h*64 + row) * K + tt*64 + scn*8,
              ldsb + w*512);
  };
  auto stageB = [&](int tt, int u) {   // u=0..2 : rows u*64..+63
    bf16_t* ldsb = Bs + (tt & 1)*12288 + u*4096;
    int row = tid >> 3;
    int scn = (tid & 7) ^ (row & 7);
    gld_lds16(Bt + ((size_t)bn*192 + u*64 + row) * K + tt*64 + scn*8,
              ldsb + w*512);
  };
  auto afrag = [&](int b2, int row, int kk) -> bf16x8 {
    int chunk = (kk*4 + lg) ^ (row & 7);
    return *(const bf16x8*)((const char*)(As + b2*8192) + row*128 + chunk*16);
  };
  auto bfrag = [&](int b2, int row, int kk) -> bf16x8 {
    int chunk = (kk*4 + lg) ^ (row & 7);
    return *(const bf16x8*)((const char*)(Bs + b2*12288) + row*128 + chunk*16);
  };

  f32x4 acc[4][3] = {};
  bf16x8 a[4][2], bb[3][2];

  // prologue: tile0 complete (5), tile1 A0,A1,B0,B1 (4)
  stageA(0, 0); stageA(0, 1); stageB(0, 0); stageB(0, 1); stageB(0, 2);
  stageA(1, 0); stageA(1, 1); stageB(1, 0); stageB(1, 1);
  asm volatile("s_waitcnt vmcnt(4)" ::: "memory");
  __builtin_amdgcn_s_barrier();

  for (int t = 0; t < NT; t++) {
    int b = t & 1;
    // ---- ph1: read all A (8) + fn0 (2); stage(t+1,B2); MFMA fn0 (8)
    #pragma unroll
    for (int fm = 0; fm < 4; fm++)
      #pragma unroll
      for (int kk = 0; kk < 2; kk++)
        a[fm][kk] = afrag(b, wr*64 + fm*16 + lr, kk);
    #pragma unroll
    for (int kk = 0; kk < 2; kk++)
      bb[0][kk] = bfrag(b, wc*48 + lr, kk);
    if (t + 1 < NT) stageB(t + 1, 2);
    __builtin_amdgcn_s_barrier();
    asm volatile("s_waitcnt lgkmcnt(0)" ::: "memory");
    __builtin_amdgcn_s_setprio(1);
    #pragma unroll
    for (int fm = 0; fm < 4; fm++)
      #pragma unroll
      for (int kk = 0; kk < 2; kk++)
        acc[fm][0] = __builtin_amdgcn_mfma_f32_16x16x32_bf16(a[fm][kk], bb[0][kk], acc[fm][0], 0, 0, 0);
    __builtin_amdgcn_s_setprio(0);
    __builtin_amdgcn_s_barrier();
    // ---- ph2: read fn1 (2); stage(t+2,A0,A1); MFMA fn1 (8)
    #pragma unroll
    for (int kk = 0; kk < 2; kk++)
      bb[1][kk] = bfrag(b, wc*48 + 16 + lr, kk);
    if (t + 2 < NT) { stageA(t + 2, 0); stageA(t + 2, 1); }
    __builtin_amdgcn_s_barrier();
    asm volatile("s_waitcnt lgkmcnt(0)" ::: "memory");
    __builtin_amdgcn_s_setprio(1);
    #pragma unroll
    for (int fm = 0; fm < 4; fm++)
      #pragma unroll
      for (int kk = 0; kk < 2; kk++)
        acc[fm][1] = __builtin_amdgcn_mfma_f32_16x16x32_bf16(a[fm][kk], bb[1][kk], acc[fm][1], 0, 0, 0);
    __builtin_amdgcn_s_setprio(0);
    __builtin_amdgcn_s_barrier();
    // ---- ph3: read fn2 (2); MFMA fn2 kk0 (4)
    #pragma unroll
    for (int kk = 0; kk < 2; kk++)
      bb[2][kk] = bfrag(b, wc*48 + 32 + lr, kk);
    __builtin_amdgcn_s_barrier();
    asm volatile("s_waitcnt lgkmcnt(0)" ::: "memory");
    __builtin_amdgcn_s_setprio(1);
    #pragma unroll
    for (int fm = 0; fm < 4; fm++)
      acc[fm][2] = __builtin_amdgcn_mfma_f32_16x16x32_bf16(a[fm][0], bb[2][0], acc[fm][2], 0, 0, 0);
    __builtin_amdgcn_s_setprio(0);
    __builtin_amdgcn_s_barrier();
    // ---- ph4: stage(t+2,B0,B1); MFMA fn2 kk1 (4); counted vmcnt
    if (t + 2 < NT) { stageB(t + 2, 0); stageB(t + 2, 1); }
    __builtin_amdgcn_s_setprio(1);
    #pragma unroll
    for (int fm = 0; fm < 4; fm++)
      acc[fm][2] = __builtin_amdgcn_mfma_f32_16x16x32_bf16(a[fm][1], bb[2][1], acc[fm][2], 0, 0, 0);
    __builtin_amdgcn_s_setprio(0);
    if (t < NT - 2) asm volatile("s_waitcnt vmcnt(4)" ::: "memory");
    else            asm volatile("s_waitcnt vmcnt(0)" ::: "memory");
    __builtin_amdgcn_s_barrier();
  }

  #pragma unroll
  for (int fm = 0; fm < 4; fm++) {
    #pragma unroll
    for (int fn = 0; fn < 3; fn++) {
      #pragma unroll
      for (int r2 = 0; r2 < 4; r2++) {
        int row = bm*128 + wr*64 + fm*16 + lg*4 + r2;
        int col = bn*192 + wc*48 + fn*16 + lr;
        Cb[(size_t)row * N + col] = (bf16_t)acc[fm][fn][r2];
      }
    }
  }
}

// ---------------- GEMM2: 8-phase AM=1 (128x256), f32 out (R9-proven, unchanged) ----------------
#define MFMA_QUAD(FM0, FN0)                                                     \
  { _Pragma("unroll") for (int fm_ = 0; fm_ < QFM; fm_++)                        \
    _Pragma("unroll") for (int fn_ = 0; fn_ < 2; fn_++)                          \
    _Pragma("unroll") for (int kk_ = 0; kk_ < 2; kk_++)                          \
      acc[(FM0)+fm_][(FN0)+fn_] = __builtin_amdgcn_mfma_f32_16x16x32_bf16(       \
          a[(FM0)+fm_][kk_], bb[(FN0)+fn_][kk_], acc[(FM0)+fm_][(FN0)+fn_], 0,0,0); }

template<bool WRITE_BF16, int AM>
__global__ __launch_bounds__(512, 2) void gemm256_kernel(
    const bf16_t* __restrict__ A, const bf16_t* __restrict__ Bt,
    bf16_t* __restrict__ Cb, float* __restrict__ Cf,
    int M, int N, int K, int NBM) {
  constexpr int BM  = AM * 128;
  constexpr int NH  = AM + 2;
  constexpr int FM2 = AM * 4;
  constexpr int QFM = AM * 2;
  __shared__ bf16_t As[2 * BM * 64];
  __shared__ bf16_t Bs[2 * 256 * 64];
  int tid = threadIdx.x;
  int w = tid >> 6, l = tid & 63, lr = l & 15, lg = l >> 4;
  int wr = w >> 2, wc = w & 3;
  int nwg = gridDim.x;
  int wg  = blockIdx.x;
  int cpx = nwg >> 3;
  int swz = (wg & 7) * cpx + (wg >> 3);
  int bm = swz % NBM, bn = swz / NBM;
  const int NT = K >> 6;

  auto stage = [&](int tt, int h) {
    int b2 = tt & 1;
    const bf16_t* G; size_t grow0; bf16_t* ldsb;
    if (h < AM) { G = A;  grow0 = (size_t)bm*BM + h*128;        ldsb = As + b2*(BM*64) + h*8192; }
    else        { G = Bt; grow0 = (size_t)bn*256 + (h-AM)*128;  ldsb = Bs + b2*16384 + (h-AM)*8192; }
    int kcol = tt * 64;
    #pragma unroll
    for (int r2 = 0; r2 < 2; r2++) {
      int L = r2*8192 + tid*16;
      int row = L >> 7;
      int chunk = (L >> 4) & 7;
      int scn = chunk ^ (row & 7);
      gld_lds16(G + (grow0 + (size_t)row) * K + kcol + scn*8,
                ldsb + r2*4096 + w*512);
    }
  };
  auto afrag = [&](int b2, int row, int kk) -> bf16x8 {
    int chunk = (kk*4 + lg) ^ (row & 7);
    return *(const bf16x8*)((const char*)(As + b2*(BM*64)) + row*128 + chunk*16);
  };
  auto bfrag = [&](int b2, int row, int kk) -> bf16x8 {
    int chunk = (kk*4 + lg) ^ (row & 7);
    return *(const bf16x8*)((const char*)(Bs + b2*16384) + row*128 + chunk*16);
  };

  f32x4 acc[FM2][4] = {};
  bf16x8 a[FM2][2], bb[4][2];

  #pragma unroll
  for (int h = 0; h < NH; h++) stage(0, h);
  #pragma unroll
  for (int h = 0; h < NH - 1; h++) stage(1, h);
  if constexpr (AM == 2) asm volatile("s_waitcnt vmcnt(6)" ::: "memory");
  else                   asm volatile("s_waitcnt vmcnt(4)" ::: "memory");
  __builtin_amdgcn_s_barrier();

  for (int t = 0; t < NT; t++) {
    int b = t & 1;
    #pragma unroll
    for (int fm = 0; fm < FM2; fm++)
      #pragma unroll
      for (int kk = 0; kk < 2; kk++)
        a[fm][kk] = afrag(b, wr*(BM/2) + fm*16 + lr, kk);
    #pragma unroll
    for (int fn = 0; fn < 2; fn++)
      #pragma unroll
      for (int kk = 0; kk < 2; kk++)
        bb[fn][kk] = bfrag(b, wc*64 + fn*16 + lr, kk);
    if (t + 1 < NT) stage(t + 1, NH - 1);
    __builtin_amdgcn_s_barrier();
    asm volatile("s_waitcnt lgkmcnt(0)" ::: "memory");
    __builtin_amdgcn_s_setprio(1);
    MFMA_QUAD(0, 0);
    __builtin_amdgcn_s_setprio(0);
    __builtin_amdgcn_s_barrier();
    #pragma unroll
    for (int fn = 2; fn < 4; fn++)
      #pragma unroll
      for (int kk = 0; kk < 2; kk++)
        bb[fn][kk] = bfrag(b, wc*64 + fn*16 + lr, kk);
    if (t + 2 < NT) stage(t + 2, 0);
    __builtin_amdgcn_s_barrier();
    asm volatile("s_waitcnt lgkmcnt(0)" ::: "memory");
    __builtin_amdgcn_s_setprio(1);
    MFMA_QUAD(0, 2);
    __builtin_amdgcn_s_setprio(0);
    __builtin_amdgcn_s_barrier();
    if (t + 2 < NT) stage(t + 2, 1);
    __builtin_amdgcn_s_barrier();
    __builtin_amdgcn_s_setprio(1);
    MFMA_QUAD(QFM, 2);
    __builtin_amdgcn_s_setprio(0);
    __builtin_amdgcn_s_barrier();
    if constexpr (AM == 2) { if (t + 2 < NT) stage(t + 2, 2); }
    __builtin_amdgcn_s_barrier();
    __builtin_amdgcn_s_setprio(1);
    MFMA_QUAD(QFM, 0);
    __builtin_amdgcn_s_setprio(0);
    if (t < NT - 2) {
      if constexpr (AM == 2) asm volatile("s_waitcnt vmcnt(6)" ::: "memory");
      else                   asm volatile("s_waitcnt vmcnt(4)" ::: "memory");
    } else {
      asm volatile("s_waitcnt vmcnt(0)" ::: "memory");
    }
    __builtin_amdgcn_s_barrier();
  }

  #pragma unroll
  for (int fm = 0; fm < FM2; fm++) {
    #pragma unroll
    for (int fn = 0; fn < 4; fn++) {
      #pragma unroll
      for (int r2 = 0; r2 < 4; r2++) {
        int row = bm*BM + wr*(BM/2) + fm*16 + lg*4 + r2;
        int col = bn*256 + wc*64 + fn*16 + lr;
        if (WRITE_BF16) Cb[(size_t)row * N + col] = (bf16_t)acc[fm][fn][r2];
        else            Cf[(size_t)row * N + col] = acc[fm][fn][r2];
      }
    }
  }
}

// ---------------- fused RMSNorm + RoPE + q-scale ----------------
__global__ __launch_bounds__(256) void normrope_kernel(bf16_t* __restrict__ qkv,
    const float* __restrict__ qw, const float* __restrict__ kw,
    const float* __restrict__ sc) {
  int t = blockIdx.x;
  int tid = threadIdx.x;
  bf16_t* qrow = qkv + (size_t)t * QKVD;
  bf16_t* krow = qrow + QD;
  __shared__ float red[8];
  float s = 0.f;
  {
    const bf16x8* p = (const bf16x8*)(qrow + tid*16);
    bf16x8 v0 = p[0], v1 = p[1];
    #pragma unroll
    for (int j = 0; j < 8; j++) { float a = (float)v0[j], b = (float)v1[j]; s += a*a + b*b; }
  }
  #pragma unroll
  for (int o = 32; o; o >>= 1) s += __shfl_xor(s, o);
  if ((tid & 63) == 0) red[tid >> 6] = s;
  float sk = 0.f;
  {
    bf16x4 v = *(const bf16x4*)(krow + tid*4);
    #pragma unroll
    for (int j = 0; j < 4; j++) { float a = (float)v[j]; sk += a*a; }
  }
  #pragma unroll
  for (int o = 32; o; o >>= 1) sk += __shfl_xor(sk, o);
  if ((tid & 63) == 0) red[4 + (tid >> 6)] = sk;
  __syncthreads();
  float rq = rsqrtf((red[0]+red[1]+red[2]+red[3]) / (float)QD + 1e-6f);
  float rk = rsqrtf((red[4]+red[5]+red[6]+red[7]) / (float)KD + 1e-6f);
  const float ascale = 0.08838834764831845f;
  for (int p = tid; p < 2048; p += 256) {
    int hh = p >> 6, i = p & 63;
    int i1 = hh*HD + i, i2 = i1 + 64;
    float x1 = (float)qrow[i1] * rq * qw[i1];
    float x2 = (float)qrow[i2] * rq * qw[i2];
    float sn = sc[(t*64 + i)*2 + 0], cs = sc[(t*64 + i)*2 + 1];
    qrow[i1] = (bf16_t)((x1*cs - x2*sn) * ascale);
    qrow[i2] = (bf16_t)((x2*cs + x1*sn) * ascale);
  }
  for (int p = tid; p < 512; p += 256) {
    int hh = p >> 6, i = p & 63;
    int i1 = hh*HD + i, i2 = i1 + 64;
    float x1 = (float)krow[i1] * rk * kw[i1];
    float x2 = (float)krow[i2] * rk * kw[i2];
    float sn = sc[(t*64 + i)*2 + 0], cs = sc[(t*64 + i)*2 + 1];
    krow[i1] = (bf16_t)(x1*cs - x2*sn);
    krow[i2] = (bf16_t)(x2*cs + x1*sn);
  }
}

// ---------------- flash attention (R13 + descending-qb tail balance) ----------------
__global__ __launch_bounds__(512, 3) void attn_kernel(const bf16_t* __restrict__ qkv,
    const int* __restrict__ positions, const int* __restrict__ seg,
    bf16_t* __restrict__ O) {
  __shared__ bf16_t Ks[64 * HD];
  __shared__ bf16_t Vt[HD * VS];
  __shared__ bf16_t P[8][16 * VS];
  int tid = threadIdx.x;
  int w = tid >> 6, l = tid & 63, lr = l & 15, lg = l >> 4;
  int qb = (gridDim.x - 1 - blockIdx.x) * 128;   // long blocks launch first
  int h = blockIdx.y;
  int kvh = h >> 2;
  int q0 = qb + w * 16;
  const bf16_t* Kg = qkv + QD + (size_t)kvh * HD;
  const bf16_t* Vg = qkv + QD + KD + (size_t)kvh * HD;

  bf16x8 qf[4];
  {
    const bf16_t* Qrow = qkv + (size_t)(q0 + lr) * QKVD + h * HD;
    #pragma unroll
    for (int c = 0; c < 4; c++) qf[c] = *(const bf16x8*)(Qrow + c*32 + lg*8);
  }
  int pos_i[4], seg_i[4];
  #pragma unroll
  for (int r = 0; r < 4; r++) { int i = q0 + lg*4 + r; pos_i[r] = positions[i]; seg_i[r] = seg[i]; }
  f32x4 o[8] = {};
  float m[4], lsum[4];
  #pragma unroll
  for (int r = 0; r < 4; r++) { m[r] = -__builtin_inff(); lsum[r] = 0.f; }

  int vkp = tid & 31, vdg = tid >> 5;
  bf16x8 vrA, vrB;

  auto issueK = [&](int j0) {
    #pragma unroll
    for (int i = 0; i < 2; i++) {
      int c = tid + i*512;
      int row = c >> 4;
      int scn = (c & 15) ^ (row & 7);
      gld_lds16(Kg + (size_t)(j0 + row) * QKVD + scn*8,
                (char*)Ks + (size_t)(i*512 + (tid & 448))*16);
    }
  };
  auto loadV = [&](int j0) {
    const bf16_t* vp = Vg + (size_t)(j0 + 2*vkp) * QKVD + vdg*8;
    vrA = *(const bf16x8*)vp;
    vrB = *(const bf16x8*)(vp + QKVD);
  };

  int jstart = qb - (WIN - 1); if (jstart < 0) jstart = 0; jstart &= ~63;
  const int jlast = qb + 64;
  loadV(jstart);
  issueK(jstart);

  for (int j0 = jstart; j0 <= jlast; j0 += 64) {
    #pragma unroll
    for (int e = 0; e < 8; e++) {
      bf16x2 pr; pr[0] = vrA[e]; pr[1] = vrB[e];
      *(bf16x2*)(Vt + (vdg*8 + e)*VS + 2*vkp) = pr;
    }
    int pj[4], sj[4];
    #pragma unroll
    for (int kt = 0; kt < 4; kt++) { int j = j0 + kt*16 + lr; pj[kt] = positions[j]; sj[kt] = seg[j]; }
    asm volatile("" ::: "memory");
    if (j0 + 64 <= jlast) loadV(j0 + 64);
    asm volatile("" ::: "memory");
    asm volatile("s_waitcnt vmcnt(2) lgkmcnt(0)" ::: "memory");
    __builtin_amdgcn_s_barrier();

    bool active = (j0 <= q0 + 15) && (j0 + 63 >= q0 - (WIN - 1));
    if (active) {
      f32x4 s[4] = {};
      __builtin_amdgcn_s_setprio(1);
      #pragma unroll
      for (int kt = 0; kt < 4; kt++) {
        int row = kt*16 + lr;
        const char* kb = (const char*)Ks + row*256;
        #pragma unroll
        for (int c = 0; c < 4; c++) {
          bf16x8 kf = *(const bf16x8*)(kb + (((c*4 + lg) ^ (row & 7)) * 16));
          s[kt] = __builtin_amdgcn_mfma_f32_16x16x32_bf16(qf[c], kf, s[kt], 0, 0, 0);
        }
      }
      __builtin_amdgcn_s_setprio(0);
      #pragma unroll
      for (int kt = 0; kt < 4; kt++) {
        #pragma unroll
        for (int r = 0; r < 4; r++) {
          bool valid = (pj[kt] <= pos_i[r]) && (pos_i[r] - pj[kt] < WIN) && (seg_i[r] == sj[kt]) && (sj[kt] != 0);
          s[kt][r] = valid ? s[kt][r] : -__builtin_inff();
        }
      }
      #pragma unroll
      for (int r = 0; r < 4; r++) {
        float smax = fmaxf(fmaxf(s[0][r], s[1][r]), fmaxf(s[2][r], s[3][r]));
        if (__any(smax > m[r] + 8.f)) {
          float rm = smax;
          #pragma unroll
          for (int o2 = 1; o2 < 16; o2 <<= 1) rm = fmaxf(rm, __shfl_xor(rm, o2));
          if (rm > m[r] + 8.f) {
            float rescale = __expf(m[r] - rm);
            lsum[r] *= rescale;
            #pragma unroll
            for (int n = 0; n < 8; n++) o[n][r] *= rescale;
            m[r] = rm;
          }
        }
        float mub = fmaxf(m[r], -1e37f);
        float p0 = __expf(s[0][r] - mub);
        float p1 = __expf(s[1][r] - mub);
        float p2 = __expf(s[2][r] - mub);
        float p3 = __expf(s[3][r] - mub);
        lsum[r] += (p0 + p1) + (p2 + p3);
        int prow = (lg*4 + r) * VS;
        P[w][prow + lr]      = (bf16_t)p0;
        P[w][prow + 16 + lr] = (bf16_t)p1;
        P[w][prow + 32 + lr] = (bf16_t)p2;
        P[w][prow + 48 + lr] = (bf16_t)p3;
      }
    }
    __builtin_amdgcn_s_barrier();
    asm volatile("" ::: "memory");

    if (j0 + 64 <= jlast) issueK(j0 + 64);
    if (active) {
      __builtin_amdgcn_s_setprio(1);
      #pragma unroll
      for (int ks = 0; ks < 2; ks++) {
        bf16x8 pa = *(const bf16x8*)(&P[w][lr*VS + ks*32 + lg*8]);
        #pragma unroll
        for (int n = 0; n < 8; n++) {
          bf16x8 vb = *(const bf16x8*)(&Vt[(n*16 + lr)*VS + ks*32 + lg*8]);
          o[n] = __builtin_amdgcn_mfma_f32_16x16x32_bf16(pa, vb, o[n], 0, 0, 0);
        }
      }
      __builtin_amdgcn_s_setprio(0);
    }
    __builtin_amdgcn_s_barrier();
  }
  #pragma unroll
  for (int r = 0; r < 4; r++) {
    float ls = lsum[r];
    #pragma unroll
    for (int o2 = 1; o2 < 16; o2 <<= 1) ls += __shfl_xor(ls, o2);
    float inv = ls > 0.f ? 1.f / ls : 0.f;
    int row = q0 + lg*4 + r;
    #pragma unroll
    for (int n = 0; n < 8; n++)
      O[(size_t)row * QD + h*HD + n*16 + lr] = (bf16_t)(o[n][r] * inv);
  }
}

// ---------------- launch ----------------
extern "C" void kernel_launch(void* const* d_in, const int* in_sizes, int n_in,
                              void* d_out, int out_size, void* d_ws, size_t ws_size,
                              hipStream_t stream) {
  (void)in_sizes; (void)n_in; (void)out_size; (void)ws_size;
  const float* x  = (const float*)d_in[0];
  const float* Wq = (const float*)d_in[1];
  const float* Wk = (const float*)d_in[2];
  const float* Wv = (const float*)d_in[3];
  const float* Wo = (const float*)d_in[4];
  const float* qw = (const float*)d_in[5];
  const float* kw = (const float*)d_in[6];
  const int*  seg = (const int*)d_in[7];
  float* out = (float*)d_out;

  char* base = (char*)d_ws;
  size_t off = 0;
  auto alloc = [&](size_t b) { void* r = base + off; off = (off + b + 255) & ~(size_t)255; return r; };
  bf16_t* xb    = (bf16_t*)alloc((size_t)T_LEN * DMODEL * 2);
  bf16_t* Wallt = (bf16_t*)alloc((size_t)QKVD * DMODEL * 2);
  bf16_t* Wot   = (bf16_t*)alloc((size_t)DMODEL * QD * 2);
  bf16_t* qkv   = (bf16_t*)alloc((size_t)T_LEN * QKVD * 2);
  int*    posi  = (int*)alloc((size_t)T_LEN * 4);
  float*  sc    = (float*)alloc((size_t)T_LEN * 64 * 2 * 4);
  bf16_t* ao    = xb;  // attention output aliases xb (xb dead after GEMM1)

  pos_kernel<<<1, 256, 0, stream>>>(seg, posi);
  sincos_kernel<<<T_LEN, 64, 0, stream>>>(posi, sc);
  cvt_kernel<<<(T_LEN * DMODEL / 8 + 255) / 256, 256, 0, stream>>>(x, xb, T_LEN * DMODEL);
  transcvt_kernel<<<dim3(QD/32, DMODEL/32), dim3(32, 8), 0, stream>>>(Wq, Wallt, DMODEL, QD);
  transcvt_kernel<<<dim3(KD/32, DMODEL/32), dim3(32, 8), 0, stream>>>(Wk, Wallt + (size_t)QD * DMODEL, DMODEL, KD);
  transcvt_kernel<<<dim3(KD/32, DMODEL/32), dim3(32, 8), 0, stream>>>(Wv, Wallt + (size_t)(QD + KD) * DMODEL, DMODEL, KD);
  transcvt_kernel<<<dim3(DMODEL/32, QD/32), dim3(32, 8), 0, stream>>>(Wo, Wot, QD, DMODEL);
  // GEMM1: 128x192 tiles -> 16 x 32 = 512 blocks, 2 blocks/CU
  gemm1_kernel<<<dim3((T_LEN/128)*(QKVD/192)), 512, 0, stream>>>(
      xb, Wallt, qkv, T_LEN, QKVD, DMODEL, T_LEN/128);
  normrope_kernel<<<T_LEN, 256, 0, stream>>>(qkv, qw, kw, sc);
  attn_kernel<<<dim3(T_LEN/128, NHEADS), 512, 0, stream>>>(qkv, posi, seg, ao);
  gemm256_kernel<false, 1><<<dim3((T_LEN/128)*(DMODEL/256)), 512, 0, stream>>>(
      ao, Wot, nullptr, out, T_LEN, DMODEL, QD, T_LEN/128);
}